// Round 5
// baseline (144.867 us; speedup 1.0000x reference)
//
#include <hip/hip_runtime.h>
#include <hip/hip_bf16.h>
#include <stdint.h>

using bf16 = __hip_bfloat16;
typedef __attribute__((ext_vector_type(8))) short bf16x8;
typedef __attribute__((ext_vector_type(4))) float f32x4;

// ---------------------------------------------------------------------------
// helpers
// ---------------------------------------------------------------------------
__device__ __forceinline__ void gload_lds16(const void* g, void* l) {
  __builtin_amdgcn_global_load_lds(
      (__attribute__((address_space(1))) void*)(g),
      (__attribute__((address_space(3))) void*)(l), 16, 0, 0);
}

__device__ __forceinline__ unsigned short bf16_bits(float f) {
  bf16 b = __float2bfloat16(f);
  return *reinterpret_cast<unsigned short*>(&b);
}

__device__ __forceinline__ float b2f(unsigned short u) {
  union { unsigned int i; float f; } x;
  x.i = ((unsigned int)u) << 16;
  return x.f;
}

// ---------------------------------------------------------------------------
// pre_x: one pass over x producing xb (bf16), xt (bf16 transpose), and
// 64-row column partial sums (part[128][1024]). 64x64 tiles, grid (16,128).
// ---------------------------------------------------------------------------
__global__ __launch_bounds__(256) void pre_x(const float* __restrict__ x,
                                             unsigned short* __restrict__ xb,
                                             unsigned short* __restrict__ xt,
                                             float* __restrict__ part) {
  __shared__ unsigned short tile[64][79];
  __shared__ float cw[4][64];
  const int r0 = blockIdx.y * 64, c0 = blockIdx.x * 64;
  const int tr = threadIdx.x >> 4;         // 0..15
  const int tc4 = (threadIdx.x & 15) * 4;  // 0,4,..,60
  float ca0 = 0.f, ca1 = 0.f, ca2 = 0.f, ca3 = 0.f;
#pragma unroll
  for (int p = 0; p < 4; ++p) {
    const int r = p * 16 + tr;
    float4 f =
        *reinterpret_cast<const float4*>(x + (size_t)(r0 + r) * 1024 + c0 + tc4);
    unsigned short u0 = bf16_bits(f.x), u1 = bf16_bits(f.y);
    unsigned short u2 = bf16_bits(f.z), u3 = bf16_bits(f.w);
    ushort4 u = {u0, u1, u2, u3};
    *reinterpret_cast<ushort4*>(xb + (size_t)(r0 + r) * 1024 + c0 + tc4) = u;
    tile[r][tc4] = u0;
    tile[r][tc4 + 1] = u1;
    tile[r][tc4 + 2] = u2;
    tile[r][tc4 + 3] = u3;
    ca0 += f.x;
    ca1 += f.y;
    ca2 += f.z;
    ca3 += f.w;
  }
  // reduce col partials over tr within wave (lanes b, b^16, b^32 span 4 tr's)
  ca0 += __shfl_xor(ca0, 16); ca0 += __shfl_xor(ca0, 32);
  ca1 += __shfl_xor(ca1, 16); ca1 += __shfl_xor(ca1, 32);
  ca2 += __shfl_xor(ca2, 16); ca2 += __shfl_xor(ca2, 32);
  ca3 += __shfl_xor(ca3, 16); ca3 += __shfl_xor(ca3, 32);
  const int lane = threadIdx.x & 63, wv = threadIdx.x >> 6;
  if (lane < 16) {
    cw[wv][lane * 4] = ca0;
    cw[wv][lane * 4 + 1] = ca1;
    cw[wv][lane * 4 + 2] = ca2;
    cw[wv][lane * 4 + 3] = ca3;
  }
  __syncthreads();
  if (threadIdx.x < 64) {
    float s = cw[0][threadIdx.x] + cw[1][threadIdx.x] + cw[2][threadIdx.x] +
              cw[3][threadIdx.x];
    part[(size_t)blockIdx.y * 1024 + c0 + threadIdx.x] = s;
  }
#pragma unroll
  for (int p = 0; p < 4; ++p) {
    const int c = p * 16 + tr;
    ushort4 u = {tile[tc4][c], tile[tc4 + 1][c], tile[tc4 + 2][c],
                 tile[tc4 + 3][c]};
    *reinterpret_cast<ushort4*>(xt + (size_t)(c0 + c) * 8192 + r0 + tc4) = u;
  }
}

// ---------------------------------------------------------------------------
// wprep: z=0 Wq->Wqx4 ([W|W|W|W] x4 dup, ld 4096), z=1 Wk->Wkext ([W|W] dup),
// z=2 Wv->Wvtb (transpose). grid (16,16,3)
// ---------------------------------------------------------------------------
__global__ __launch_bounds__(256) void wprep(
    const float* __restrict__ Wq, const float* __restrict__ Wk,
    const float* __restrict__ Wv, unsigned short* __restrict__ Wqx4,
    unsigned short* __restrict__ Wkext, unsigned short* __restrict__ Wvtb) {
  __shared__ unsigned short tile[64][79];
  const int r0 = blockIdx.y * 64, c0 = blockIdx.x * 64;
  const int tr = threadIdx.x >> 4;
  const int tc4 = (threadIdx.x & 15) * 4;
  if (blockIdx.z < 2) {
    const float* W = (blockIdx.z == 0) ? Wq : Wk;
#pragma unroll
    for (int p = 0; p < 4; ++p) {
      const int r = r0 + p * 16 + tr;
      float4 f = *reinterpret_cast<const float4*>(W + (size_t)r * 1024 + c0 + tc4);
      ushort4 u = {bf16_bits(f.x), bf16_bits(f.y), bf16_bits(f.z), bf16_bits(f.w)};
      if (blockIdx.z == 0) {
#pragma unroll
        for (int rep = 0; rep < 4; ++rep)
          *reinterpret_cast<ushort4*>(Wqx4 + (size_t)r * 4096 + rep * 1024 + c0 +
                                      tc4) = u;
      } else {
        *reinterpret_cast<ushort4*>(Wkext + (size_t)r * 2048 + c0 + tc4) = u;
        *reinterpret_cast<ushort4*>(Wkext + (size_t)r * 2048 + 1024 + c0 + tc4) = u;
      }
    }
  } else {
#pragma unroll
    for (int p = 0; p < 4; ++p) {
      const int r = p * 16 + tr;
      float4 f =
          *reinterpret_cast<const float4*>(Wv + (size_t)(r0 + r) * 1024 + c0 + tc4);
      tile[r][tc4] = bf16_bits(f.x);
      tile[r][tc4 + 1] = bf16_bits(f.y);
      tile[r][tc4 + 2] = bf16_bits(f.z);
      tile[r][tc4 + 3] = bf16_bits(f.w);
    }
    __syncthreads();
#pragma unroll
    for (int p = 0; p < 4; ++p) {
      const int c = p * 16 + tr;
      ushort4 u = {tile[tc4][c], tile[tc4 + 1][c], tile[tc4 + 2][c],
                   tile[tc4 + 3][c]};
      *reinterpret_cast<ushort4*>(Wvtb + (size_t)(c0 + c) * 1024 + r0 + tc4) = u;
    }
  }
}

// sv[c] = sum over 128 row-stripes of part
__global__ __launch_bounds__(256) void colsum_final(const float* __restrict__ part,
                                                    float* __restrict__ sv) {
  const int c = blockIdx.x * 256 + threadIdx.x;
  float s = 0.f;
  for (int p = 0; p < 128; ++p) s += part[(size_t)p * 1024 + c];
  sv[c] = s;
}

// u = Wq*s (rows 0..1023 of uw), w = Wk*s (rows 1024..2047); one wave per row
__global__ __launch_bounds__(256) void matvec2(const float* __restrict__ Wq,
                                               const float* __restrict__ Wk,
                                               const float* __restrict__ sv,
                                               float* __restrict__ uw) {
  const int row = blockIdx.x * 4 + (threadIdx.x >> 6);
  const int lane = threadIdx.x & 63;
  const float* W = (row < 1024) ? (Wq + (size_t)row * 1024)
                                : (Wk + (size_t)(row - 1024) * 1024);
  const int c0 = lane * 16;
  float acc = 0.f;
#pragma unroll
  for (int q = 0; q < 4; ++q) {
    float4 wv4 = *reinterpret_cast<const float4*>(W + c0 + q * 4);
    float4 s4 = *reinterpret_cast<const float4*>(sv + c0 + q * 4);
    acc += wv4.x * s4.x + wv4.y * s4.y + wv4.z * s4.z + wv4.w * s4.w;
  }
#pragma unroll
  for (int off = 32; off; off >>= 1) acc += __shfl_xor(acc, off);
  if (lane == 0) uw[row] = acc;
}

// ---------------------------------------------------------------------------
// NT GEMM, single-buffered m97 structure (32KB LDS -> 4-5 blocks/CU):
//   per K-step: stage (8x gload_lds16) -> sync -> ds_read+MFMA -> sync.
//   128x128 tile, BK=64, 4 waves, T2 XOR-swizzled LDS via pre-swizzled
//   global source. Cross-block wave overlap hides the barrier drain (m114).
// BIAS_MODE: 0 none, 2 bias[col]. OUT_BF16: 1 -> bf16 C. XCD_SWZ: T1 swizzle.
// CONCAT: 1 -> bf16 partials written column-concatenated:
//   C[row][blockIdx.z*N + col], row stride gridDim.z*N (no reduce node).
// ---------------------------------------------------------------------------
template <int BIAS_MODE, int OUT_BF16, int XCD_SWZ, int CONCAT>
__global__ __launch_bounds__(256, 4) void gemm_nt(
    const bf16* __restrict__ A, const bf16* __restrict__ B,
    const float* __restrict__ bias, void* __restrict__ Cout, int M, int N,
    int K, int kChunk, float scale) {
  __shared__ __align__(128) char lds[32768];  // A @0, B @16384
  const int tid = threadIdx.x;
  const int lane = tid & 63;
  const int wv = tid >> 6;
  const int wm = wv >> 1, wn = wv & 1;

  int mt, nt;
  if (XCD_SWZ) {
    int lin = blockIdx.y * gridDim.x + blockIdx.x;
    int cpx = (gridDim.x * gridDim.y) >> 3;  // nwg % 8 == 0 required
    int swz = (lin & 7) * cpx + (lin >> 3);
    nt = swz % gridDim.x;
    mt = swz / gridDim.x;
  } else {
    nt = blockIdx.x;
    mt = blockIdx.y;
  }
  const int m0 = mt * 128, n0 = nt * 128;
  const int kBegin = blockIdx.z * kChunk;

  const char* srcA[4];
  const char* srcB[4];
  int dstOff[4];
#pragma unroll
  for (int t = 0; t < 4; ++t) {
    int o = wv * 4096 + t * 1024 + lane * 16;  // linear LDS byte offset
    int row = o >> 7;                          // tile row (128B per row)
    int gcb = (o & 127) ^ ((row & 7) << 4);    // inverse-swizzled global col
    srcA[t] = (const char*)A + ((size_t)(m0 + row) * K + kBegin) * 2 + gcb;
    srcB[t] = (const char*)B + ((size_t)(n0 + row) * K + kBegin) * 2 + gcb;
    dstOff[t] = wv * 4096 + t * 1024;
  }

  const int xorv = (lane & 7) << 4;
  const int rowOff = (lane & 15) * 128;
  const int colHi = (lane >> 4) << 4;

  f32x4 acc[4][4] = {};
  const int nk = kChunk >> 6;
  for (int kt = 0; kt < nk; ++kt) {
#pragma unroll
    for (int t = 0; t < 4; ++t) gload_lds16(srcA[t], lds + dstOff[t]);
#pragma unroll
    for (int t = 0; t < 4; ++t) gload_lds16(srcB[t], lds + 16384 + dstOff[t]);
#pragma unroll
    for (int t = 0; t < 4; ++t) {
      srcA[t] += 128;  // advance 64 bf16 in k
      srcB[t] += 128;
    }
    __syncthreads();  // drains vmcnt -> tile visible to all waves
#pragma unroll
    for (int h = 0; h < 2; ++h) {
      const int kk64 = h * 64;
      bf16x8 af[4], bfr[4];
#pragma unroll
      for (int f = 0; f < 4; ++f)
        af[f] = *reinterpret_cast<const bf16x8*>(
            lds + ((wm * 64 + f * 16) * 128) + rowOff + ((kk64 + colHi) ^ xorv));
#pragma unroll
      for (int f = 0; f < 4; ++f)
        bfr[f] = *reinterpret_cast<const bf16x8*>(
            lds + 16384 + ((wn * 64 + f * 16) * 128) + rowOff +
            ((kk64 + colHi) ^ xorv));
      __builtin_amdgcn_s_setprio(1);
#pragma unroll
      for (int m = 0; m < 4; ++m)
#pragma unroll
        for (int n = 0; n < 4; ++n)
          acc[m][n] = __builtin_amdgcn_mfma_f32_16x16x32_bf16(af[m], bfr[n],
                                                              acc[m][n], 0, 0, 0);
      __builtin_amdgcn_s_setprio(0);
    }
    __syncthreads();  // all waves done reading before next stage
  }

  // epilogue: C/D layout col=lane&15, row=(lane>>4)*4+r (guide §3, m89)
  const int ldC = CONCAT ? (int)(gridDim.z * N) : N;
  const int cOff = CONCAT ? (int)(blockIdx.z * N) : 0;
  char* Cbase = (char*)Cout;
  if (!CONCAT) Cbase += (size_t)blockIdx.z * M * N * (OUT_BF16 ? 2 : 4);
#pragma unroll
  for (int m = 0; m < 4; ++m) {
    const int grow = m0 + wm * 64 + m * 16 + ((lane >> 4) << 2);
#pragma unroll
    for (int n = 0; n < 4; ++n) {
      const int gcol = n0 + wn * 64 + n * 16 + (lane & 15);
#pragma unroll
      for (int r = 0; r < 4; ++r) {
        float v = acc[m][n][r] * scale;
        if (BIAS_MODE == 2) v += bias[gcol];
        if (OUT_BF16)
          ((bf16*)Cbase)[(size_t)(grow + r) * ldC + cOff + gcol] =
              __float2bfloat16(v);
        else
          ((float*)Cbase)[(size_t)(grow + r) * ldC + cOff + gcol] = v;
      }
    }
  }
}

// ---------------------------------------------------------------------------
// sum 8 split-K partials of G = x^T x, emit Gext = [bf16(G) | bf16(residual)]
// ---------------------------------------------------------------------------
__global__ __launch_bounds__(256) void gext_sum(const float* __restrict__ Sp,
                                                unsigned short* __restrict__ Gext) {
  const int k = blockIdx.x;
  const int c4 = threadIdx.x * 4;
  float g[4] = {0.f, 0.f, 0.f, 0.f};
#pragma unroll
  for (int z = 0; z < 8; ++z) {
    float4 f = *reinterpret_cast<const float4*>(Sp + ((size_t)z << 20) +
                                                (size_t)k * 1024 + c4);
    g[0] += f.x;
    g[1] += f.y;
    g[2] += f.z;
    g[3] += f.w;
  }
  ushort4 hi, lo;
  unsigned short* h = &hi.x;
  unsigned short* l = &lo.x;
#pragma unroll
  for (int q = 0; q < 4; ++q) {
    unsigned short b = bf16_bits(g[q]);
    h[q] = b;
    l[q] = bf16_bits(g[q] - b2f(b));
  }
  *reinterpret_cast<ushort4*>(Gext + (size_t)k * 2048 + c4) = hi;
  *reinterpret_cast<ushort4*>(Gext + (size_t)k * 2048 + 1024 + c4) = lo;
}

// ---------------------------------------------------------------------------
// row-softmax over 4 St split-K partials with rank-1 bias corrections and
// fused r[j] = atten[:,j].bv
// v[i] = norm*(sum_z Stp[z][j][i] + bk[j]*u[i] + (w[j]+8192*bk[j])*bq[i])
// ---------------------------------------------------------------------------
__global__ __launch_bounds__(256) void softmax_corr_r(
    const float* __restrict__ Stp, const float* __restrict__ uw,
    const float* __restrict__ bq, const float* __restrict__ bk,
    const float* __restrict__ bv, bf16* __restrict__ At,
    float* __restrict__ rv) {
  const int j = blockIdx.x;
  const int tid = threadIdx.x;
  const int lane = tid & 63, wv = tid >> 6;
  const float a1 = bk[j];
  const float a2 = uw[1024 + j] + 8192.0f * a1;
  const float norm = 0.03125f;  // 1/sqrt(1024)
  float v[4];
#pragma unroll
  for (int t = 0; t < 4; ++t) {
    const int i = tid + 256 * t;
    float s = 0.f;
#pragma unroll
    for (int z = 0; z < 4; ++z)
      s += Stp[((size_t)z << 20) + (size_t)j * 1024 + i];
    v[t] = norm * (s + a1 * uw[i] + a2 * bq[i]);
  }
  float m = fmaxf(fmaxf(v[0], v[1]), fmaxf(v[2], v[3]));
#pragma unroll
  for (int off = 32; off; off >>= 1) m = fmaxf(m, __shfl_xor(m, off));
  __shared__ float red[12];
  if (lane == 0) red[wv] = m;
  __syncthreads();
  m = fmaxf(fmaxf(red[0], red[1]), fmaxf(red[2], red[3]));
  float p[4], s = 0.f, pr = 0.f;
#pragma unroll
  for (int t = 0; t < 4; ++t) {
    p[t] = __expf(v[t] - m);
    s += p[t];
    pr += p[t] * bv[tid + 256 * t];
  }
#pragma unroll
  for (int off = 32; off; off >>= 1) {
    s += __shfl_xor(s, off);
    pr += __shfl_xor(pr, off);
  }
  if (lane == 0) {
    red[4 + wv] = s;
    red[8 + wv] = pr;
  }
  __syncthreads();
  const float inv = 1.f / (red[4] + red[5] + red[6] + red[7]);
#pragma unroll
  for (int t = 0; t < 4; ++t)
    At[(size_t)j * 1024 + tid + 256 * t] = __float2bfloat16(p[t] * inv);
  if (tid == 0) rv[j] = (red[8] + red[9] + red[10] + red[11]) * inv;
}

// ---------------------------------------------------------------------------
extern "C" void kernel_launch(void* const* d_in, const int* in_sizes, int n_in,
                              void* d_out, int out_size, void* d_ws,
                              size_t ws_size, hipStream_t stream) {
  const float* x = (const float*)d_in[0];
  const float* Wq = (const float*)d_in[1];
  const float* bq = (const float*)d_in[2];
  const float* Wk = (const float*)d_in[3];
  const float* bk = (const float*)d_in[4];
  const float* Wv = (const float*)d_in[5];
  const float* bv = (const float*)d_in[6];
  (void)in_sizes;
  (void)n_in;
  (void)out_size;
  (void)ws_size;

  char* ws = (char*)d_ws;
  const size_t MB = 1ull << 20;
  bf16* xb = (bf16*)(ws);                // [8192][1024], 16MB
  bf16* xt = (bf16*)(ws + 16 * MB);      // [1024][8192], 16MB
  float* SpG = (float*)(ws + 32 * MB);   // [8][1024][1024] f32, 32MB
  bf16* Wkext = (bf16*)(ws + 64 * MB);   // [1024][2048], 4MB
  bf16* Wqx4 = (bf16*)(ws + 68 * MB);    // [1024][4096] (Wq x4), 8MB
  bf16* Wvtb = (bf16*)(ws + 76 * MB);    // [1024][1024] (Wv^T), 2MB
  bf16* Gext = (bf16*)(ws + 78 * MB);    // [1024][2048], 4MB
  bf16* T1x = (bf16*)(ws + 82 * MB);     // [1024][4096] (T1 z-concat), 8MB
  float* Stp = (float*)(ws + 90 * MB);   // [4][1024][1024] f32, 16MB
  bf16* At = (bf16*)(ws + 106 * MB);     // [1024][1024], 2MB
  bf16* Ftb = (bf16*)(ws + 108 * MB);    // [1024][1024], 2MB
  float* sv = (float*)(ws + 110 * MB);          // [1024]
  float* uw = (float*)(ws + 110 * MB + 4096);   // [2048]
  float* rv = (float*)(ws + 110 * MB + 16384);  // [1024]
  float* part = (float*)(ws + 111 * MB);        // [128][1024] f32, 512KB

  // 1. x -> xb, xt, column partials (single pass over x)
  pre_x<<<dim3(16, 128), 256, 0, stream>>>(x, (unsigned short*)xb,
                                           (unsigned short*)xt, part);
  // 2. weights: Wq->Wqx4 (x4 dup), Wk->Wkext (dup), Wv->Wvtb (transpose)
  wprep<<<dim3(16, 16, 3), 256, 0, stream>>>(Wq, Wk, Wv, (unsigned short*)Wqx4,
                                             (unsigned short*)Wkext,
                                             (unsigned short*)Wvtb);
  // 3. sv = colsum(x)
  colsum_final<<<4, 256, 0, stream>>>(part, sv);
  // 4. u = Wq s, w = Wk s
  matvec2<<<512, 256, 0, stream>>>(Wq, Wk, sv, uw);
  // 5. G = x^T x : NT(xt, xt), K=8192, split-K=8 -> f32 partials (512 blocks)
  gemm_nt<0, 0, 1, 0><<<dim3(8, 8, 8), 256, 0, stream>>>(
      xt, xt, nullptr, SpG, 1024, 1024, 8192, 1024, 1.0f);
  // 6. Gext = [bf16(G) | residual]
  gext_sum<<<1024, 256, 0, stream>>>(SpG, (unsigned short*)Gext);
  // 7. T1 = Wk*G, split-K=4, bf16 col-concat -> T1x[1024][4096] (256 blocks)
  gemm_nt<0, 1, 0, 1><<<dim3(8, 8, 4), 256, 0, stream>>>(
      Wkext, Gext, nullptr, T1x, 1024, 1024, 2048, 512, 1.0f);
  // 8. St = T1x * Wqx4^T (K=4096), split-K=4 -> f32 partials (256 blocks)
  gemm_nt<0, 0, 0, 0><<<dim3(8, 8, 4), 256, 0, stream>>>(
      T1x, Wqx4, nullptr, Stp, 1024, 1024, 4096, 1024, 1.0f);
  // 9. atten^T = softmax over summed partials + corrections; r = atten^T.bv
  softmax_corr_r<<<1024, 256, 0, stream>>>(Stp, uw, bq, bk, bv, At, rv);
  // 10. F^T = NT(At, Wvt) -> bf16   (F = Wv^T atten)
  gemm_nt<0, 1, 1, 0><<<dim3(8, 8), 256, 0, stream>>>(
      At, Wvtb, nullptr, Ftb, 1024, 1024, 1024, 1024, 1.0f);
  // 11. out = x * F + 1*r^T : NT(xb, Ftb) + bias[col] -> f32 d_out
  gemm_nt<2, 0, 1, 0><<<dim3(8, 64), 256, 0, stream>>>(
      xb, Ftb, rv, d_out, 8192, 1024, 1024, 1024, 1.0f);
}

// Round 6
// 124.145 us; speedup vs baseline: 1.1669x; 1.1669x over previous
//
#include <hip/hip_runtime.h>
#include <hip/hip_bf16.h>
#include <stdint.h>

using bf16 = __hip_bfloat16;
typedef __attribute__((ext_vector_type(8))) short bf16x8;
typedef __attribute__((ext_vector_type(4))) float f32x4;

// ---------------------------------------------------------------------------
// helpers
// ---------------------------------------------------------------------------
__device__ __forceinline__ void gload_lds16(const void* g, void* l) {
  __builtin_amdgcn_global_load_lds(
      (__attribute__((address_space(1))) void*)(g),
      (__attribute__((address_space(3))) void*)(l), 16, 0, 0);
}

__device__ __forceinline__ unsigned short bf16_bits(float f) {
  bf16 b = __float2bfloat16(f);
  return *reinterpret_cast<unsigned short*>(&b);
}

__device__ __forceinline__ float b2f(unsigned short u) {
  union { unsigned int i; float f; } x;
  x.i = ((unsigned int)u) << 16;
  return x.f;
}

// ---------------------------------------------------------------------------
// pre_all: grid (16, 176).
//  y in [0,128):  x-tiles -> xb (bf16), xt (bf16 transpose), part (col sums)
//  y in [128,144): Wq stripes -> Wqx2 ([W|W] dup, ld 2048)
//  y in [144,160): Wk stripes -> Wkext ([W|W] dup, ld 2048)
//  y in [160,176): Wv stripes -> Wvtb (bf16 transpose)
// ---------------------------------------------------------------------------
__global__ __launch_bounds__(256) void pre_all(
    const float* __restrict__ x, const float* __restrict__ Wq,
    const float* __restrict__ Wk, const float* __restrict__ Wv,
    unsigned short* __restrict__ xb, unsigned short* __restrict__ xt,
    float* __restrict__ part, unsigned short* __restrict__ Wqx2,
    unsigned short* __restrict__ Wkext, unsigned short* __restrict__ Wvtb) {
  __shared__ unsigned short tile[64][79];
  __shared__ float cw[4][64];
  const int by = blockIdx.y;
  const int c0 = blockIdx.x * 64;
  const int tr = threadIdx.x >> 4;         // 0..15
  const int tc4 = (threadIdx.x & 15) * 4;  // 0,4,..,60

  if (by < 128) {
    const int r0 = by * 64;
    float ca0 = 0.f, ca1 = 0.f, ca2 = 0.f, ca3 = 0.f;
#pragma unroll
    for (int p = 0; p < 4; ++p) {
      const int r = p * 16 + tr;
      float4 f =
          *reinterpret_cast<const float4*>(x + (size_t)(r0 + r) * 1024 + c0 + tc4);
      unsigned short u0 = bf16_bits(f.x), u1 = bf16_bits(f.y);
      unsigned short u2 = bf16_bits(f.z), u3 = bf16_bits(f.w);
      ushort4 u = {u0, u1, u2, u3};
      *reinterpret_cast<ushort4*>(xb + (size_t)(r0 + r) * 1024 + c0 + tc4) = u;
      tile[r][tc4] = u0;
      tile[r][tc4 + 1] = u1;
      tile[r][tc4 + 2] = u2;
      tile[r][tc4 + 3] = u3;
      ca0 += f.x;
      ca1 += f.y;
      ca2 += f.z;
      ca3 += f.w;
    }
    ca0 += __shfl_xor(ca0, 16); ca0 += __shfl_xor(ca0, 32);
    ca1 += __shfl_xor(ca1, 16); ca1 += __shfl_xor(ca1, 32);
    ca2 += __shfl_xor(ca2, 16); ca2 += __shfl_xor(ca2, 32);
    ca3 += __shfl_xor(ca3, 16); ca3 += __shfl_xor(ca3, 32);
    const int lane = threadIdx.x & 63, wv = threadIdx.x >> 6;
    if (lane < 16) {
      cw[wv][lane * 4] = ca0;
      cw[wv][lane * 4 + 1] = ca1;
      cw[wv][lane * 4 + 2] = ca2;
      cw[wv][lane * 4 + 3] = ca3;
    }
    __syncthreads();
    if (threadIdx.x < 64) {
      float s = cw[0][threadIdx.x] + cw[1][threadIdx.x] + cw[2][threadIdx.x] +
                cw[3][threadIdx.x];
      part[(size_t)by * 1024 + c0 + threadIdx.x] = s;
    }
#pragma unroll
    for (int p = 0; p < 4; ++p) {
      const int c = p * 16 + tr;
      ushort4 u = {tile[tc4][c], tile[tc4 + 1][c], tile[tc4 + 2][c],
                   tile[tc4 + 3][c]};
      *reinterpret_cast<ushort4*>(xt + (size_t)(c0 + c) * 8192 + r0 + tc4) = u;
    }
  } else {
    const int w = by - 128;
    const int widx = w >> 4;          // 0=Wq,1=Wk,2=Wv
    const int r0 = (w & 15) * 64;
    if (widx < 2) {
      const float* W = (widx == 0) ? Wq : Wk;
      unsigned short* out = (widx == 0) ? Wqx2 : Wkext;
#pragma unroll
      for (int p = 0; p < 4; ++p) {
        const int r = r0 + p * 16 + tr;
        float4 f =
            *reinterpret_cast<const float4*>(W + (size_t)r * 1024 + c0 + tc4);
        ushort4 u = {bf16_bits(f.x), bf16_bits(f.y), bf16_bits(f.z),
                     bf16_bits(f.w)};
        *reinterpret_cast<ushort4*>(out + (size_t)r * 2048 + c0 + tc4) = u;
        *reinterpret_cast<ushort4*>(out + (size_t)r * 2048 + 1024 + c0 + tc4) = u;
      }
    } else {
#pragma unroll
      for (int p = 0; p < 4; ++p) {
        const int r = p * 16 + tr;
        float4 f = *reinterpret_cast<const float4*>(Wv + (size_t)(r0 + r) * 1024 +
                                                    c0 + tc4);
        tile[r][tc4] = bf16_bits(f.x);
        tile[r][tc4 + 1] = bf16_bits(f.y);
        tile[r][tc4 + 2] = bf16_bits(f.z);
        tile[r][tc4 + 3] = bf16_bits(f.w);
      }
      __syncthreads();
#pragma unroll
      for (int p = 0; p < 4; ++p) {
        const int c = p * 16 + tr;
        ushort4 u = {tile[tc4][c], tile[tc4 + 1][c], tile[tc4 + 2][c],
                     tile[tc4 + 3][c]};
        *reinterpret_cast<ushort4*>(Wvtb + (size_t)(c0 + c) * 1024 + r0 + tc4) = u;
      }
    }
  }
}

// ---------------------------------------------------------------------------
// sv_uw: fused colsum + matvec. 128 blocks x 256 threads.
// Phase 1: sv (column sums of x) rebuilt per-block from part[128][1024] (LDS).
// Phase 2: each block computes 16 rows of uw = [Wq;Wk] . sv
// ---------------------------------------------------------------------------
__global__ __launch_bounds__(256) void sv_uw(const float* __restrict__ part,
                                             const float* __restrict__ Wq,
                                             const float* __restrict__ Wk,
                                             float* __restrict__ uw) {
  __shared__ float svl[1024];
  const int tid = threadIdx.x;
  float4 a = {0.f, 0.f, 0.f, 0.f};
  for (int p = 0; p < 128; ++p) {
    float4 f = *reinterpret_cast<const float4*>(part + (size_t)p * 1024 + tid * 4);
    a.x += f.x;
    a.y += f.y;
    a.z += f.z;
    a.w += f.w;
  }
  *reinterpret_cast<float4*>(svl + tid * 4) = a;
  __syncthreads();

  const int lane = tid & 63, wv = tid >> 6;
  const int lane16 = lane & 15, rsub = lane >> 4;
  const int row = blockIdx.x * 16 + wv * 4 + rsub;
  const float* W = (row < 1024) ? (Wq + (size_t)row * 1024)
                                : (Wk + (size_t)(row - 1024) * 1024);
  float acc = 0.f;
#pragma unroll
  for (int q = 0; q < 16; ++q) {
    const int c = (lane16 + q * 16) * 4;
    float4 wv4 = *reinterpret_cast<const float4*>(W + c);
    float4 s4 = *reinterpret_cast<const float4*>(svl + c);
    acc += wv4.x * s4.x + wv4.y * s4.y + wv4.z * s4.z + wv4.w * s4.w;
  }
#pragma unroll
  for (int off = 1; off < 16; off <<= 1) acc += __shfl_xor(acc, off);
  if (lane16 == 0) uw[row] = acc;
}

// ---------------------------------------------------------------------------
// NT GEMM, 2-phase double-buffered (R4 structure, 64KB LDS, 2 blocks/CU):
//   prologue STAGE(buf0); per iter: STAGE(buf^1) -> ds_read+MFMA(buf) ->
//   one __syncthreads() -> swap. 128x128 tile, BK=64, 4 waves, T2 swizzle.
// BIAS_MODE: 0 none, 2 bias[col]. OUT_BF16: 1 -> bf16 C. XCD_SWZ: T1 swizzle.
// CONCAT: 1 -> partials column-concatenated C[row][z*N+col], ld gridDim.z*N.
// ---------------------------------------------------------------------------
template <int BIAS_MODE, int OUT_BF16, int XCD_SWZ, int CONCAT>
__global__ __launch_bounds__(256, 2) void gemm_nt(
    const bf16* __restrict__ A, const bf16* __restrict__ B,
    const float* __restrict__ bias, void* __restrict__ Cout, int M, int N,
    int K, int kChunk, float scale) {
  __shared__ __align__(128) char lds[65536];  // A: [2][16KB] @0, B: @32768
  const int tid = threadIdx.x;
  const int lane = tid & 63;
  const int wv = tid >> 6;
  const int wm = wv >> 1, wn = wv & 1;

  int mt, nt;
  if (XCD_SWZ) {
    int lin = blockIdx.y * gridDim.x + blockIdx.x;
    int cpx = (gridDim.x * gridDim.y) >> 3;  // nwg % 8 == 0 required
    int swz = (lin & 7) * cpx + (lin >> 3);
    nt = swz % gridDim.x;
    mt = swz / gridDim.x;
  } else {
    nt = blockIdx.x;
    mt = blockIdx.y;
  }
  const int m0 = mt * 128, n0 = nt * 128;
  const int kBegin = blockIdx.z * kChunk;

  const char* srcA[4];
  const char* srcB[4];
  int dstOff[4];
#pragma unroll
  for (int t = 0; t < 4; ++t) {
    int o = wv * 4096 + t * 1024 + lane * 16;  // linear LDS byte offset
    int row = o >> 7;                          // tile row (128B per row)
    int gcb = (o & 127) ^ ((row & 7) << 4);    // inverse-swizzled global col
    srcA[t] = (const char*)A + ((size_t)(m0 + row) * K + kBegin) * 2 + gcb;
    srcB[t] = (const char*)B + ((size_t)(n0 + row) * K + kBegin) * 2 + gcb;
    dstOff[t] = wv * 4096 + t * 1024;
  }

  const int xorv = (lane & 7) << 4;
  const int rowOff = (lane & 15) * 128;
  const int colHi = (lane >> 4) << 4;

  // prologue: stage tile 0 into buf 0
#pragma unroll
  for (int t = 0; t < 4; ++t) gload_lds16(srcA[t], lds + dstOff[t]);
#pragma unroll
  for (int t = 0; t < 4; ++t) gload_lds16(srcB[t], lds + 32768 + dstOff[t]);
#pragma unroll
  for (int t = 0; t < 4; ++t) {
    srcA[t] += 128;
    srcB[t] += 128;
  }
  __syncthreads();

  f32x4 acc[4][4] = {};
  const int nk = kChunk >> 6;
  int cur = 0;
  for (int kt = 0; kt < nk; ++kt) {
    if (kt + 1 < nk) {  // prefetch next tile into the other buffer
      const int nb = (cur ^ 1) * 16384;
#pragma unroll
      for (int t = 0; t < 4; ++t) gload_lds16(srcA[t], lds + nb + dstOff[t]);
#pragma unroll
      for (int t = 0; t < 4; ++t)
        gload_lds16(srcB[t], lds + 32768 + nb + dstOff[t]);
#pragma unroll
      for (int t = 0; t < 4; ++t) {
        srcA[t] += 128;
        srcB[t] += 128;
      }
    }
    const char* baseA = lds + cur * 16384;
    const char* baseB = lds + 32768 + cur * 16384;
#pragma unroll
    for (int h = 0; h < 2; ++h) {
      const int kk64 = h * 64;
      bf16x8 af[4], bfr[4];
#pragma unroll
      for (int f = 0; f < 4; ++f)
        af[f] = *reinterpret_cast<const bf16x8*>(
            baseA + ((wm * 64 + f * 16) * 128) + rowOff + ((kk64 + colHi) ^ xorv));
#pragma unroll
      for (int f = 0; f < 4; ++f)
        bfr[f] = *reinterpret_cast<const bf16x8*>(
            baseB + ((wn * 64 + f * 16) * 128) + rowOff + ((kk64 + colHi) ^ xorv));
      __builtin_amdgcn_s_setprio(1);
#pragma unroll
      for (int m = 0; m < 4; ++m)
#pragma unroll
        for (int n = 0; n < 4; ++n)
          acc[m][n] = __builtin_amdgcn_mfma_f32_16x16x32_bf16(af[m], bfr[n],
                                                              acc[m][n], 0, 0, 0);
      __builtin_amdgcn_s_setprio(0);
    }
    __syncthreads();  // staged loads drained; all waves done reading cur
    cur ^= 1;
  }

  // epilogue: C/D layout col=lane&15, row=(lane>>4)*4+r (guide §3, m89)
  const int ldC = CONCAT ? (int)(gridDim.z * N) : N;
  const int cOff = CONCAT ? (int)(blockIdx.z * N) : 0;
  char* Cbase = (char*)Cout;
  if (!CONCAT) Cbase += (size_t)blockIdx.z * M * N * (OUT_BF16 ? 2 : 4);
#pragma unroll
  for (int m = 0; m < 4; ++m) {
    const int grow = m0 + wm * 64 + m * 16 + ((lane >> 4) << 2);
#pragma unroll
    for (int n = 0; n < 4; ++n) {
      const int gcol = n0 + wn * 64 + n * 16 + (lane & 15);
#pragma unroll
      for (int r = 0; r < 4; ++r) {
        float v = acc[m][n][r] * scale;
        if (BIAS_MODE == 2) v += bias[gcol];
        if (OUT_BF16)
          ((bf16*)Cbase)[(size_t)(grow + r) * ldC + cOff + gcol] =
              __float2bfloat16(v);
        else
          ((float*)Cbase)[(size_t)(grow + r) * ldC + cOff + gcol] = v;
      }
    }
  }
}

// ---------------------------------------------------------------------------
// sum 8 split-K partials of G = x^T x, emit Gext = [bf16(G) | bf16(residual)]
// ---------------------------------------------------------------------------
__global__ __launch_bounds__(256) void gext_sum(const float* __restrict__ Sp,
                                                unsigned short* __restrict__ Gext) {
  const int k = blockIdx.x;
  const int c4 = threadIdx.x * 4;
  float g[4] = {0.f, 0.f, 0.f, 0.f};
#pragma unroll
  for (int z = 0; z < 8; ++z) {
    float4 f = *reinterpret_cast<const float4*>(Sp + ((size_t)z << 20) +
                                                (size_t)k * 1024 + c4);
    g[0] += f.x;
    g[1] += f.y;
    g[2] += f.z;
    g[3] += f.w;
  }
  ushort4 hi, lo;
  unsigned short* h = &hi.x;
  unsigned short* l = &lo.x;
#pragma unroll
  for (int q = 0; q < 4; ++q) {
    unsigned short b = bf16_bits(g[q]);
    h[q] = b;
    l[q] = bf16_bits(g[q] - b2f(b));
  }
  *reinterpret_cast<ushort4*>(Gext + (size_t)k * 2048 + c4) = hi;
  *reinterpret_cast<ushort4*>(Gext + (size_t)k * 2048 + 1024 + c4) = lo;
}

// ---------------------------------------------------------------------------
// row-softmax over 2 St split-K partials with rank-1 bias corrections and
// fused r[j] = atten[:,j].bv
// ---------------------------------------------------------------------------
__global__ __launch_bounds__(256) void softmax_corr_r(
    const float* __restrict__ Stp, const float* __restrict__ uw,
    const float* __restrict__ bq, const float* __restrict__ bk,
    const float* __restrict__ bv, bf16* __restrict__ At,
    float* __restrict__ rv) {
  const int j = blockIdx.x;
  const int tid = threadIdx.x;
  const int lane = tid & 63, wv = tid >> 6;
  const float a1 = bk[j];
  const float a2 = uw[1024 + j] + 8192.0f * a1;
  const float norm = 0.03125f;  // 1/sqrt(1024)
  float v[4];
#pragma unroll
  for (int t = 0; t < 4; ++t) {
    const int i = tid + 256 * t;
    float s = Stp[(size_t)j * 1024 + i] + Stp[(1ull << 20) + (size_t)j * 1024 + i];
    v[t] = norm * (s + a1 * uw[i] + a2 * bq[i]);
  }
  float m = fmaxf(fmaxf(v[0], v[1]), fmaxf(v[2], v[3]));
#pragma unroll
  for (int off = 32; off; off >>= 1) m = fmaxf(m, __shfl_xor(m, off));
  __shared__ float red[12];
  if (lane == 0) red[wv] = m;
  __syncthreads();
  m = fmaxf(fmaxf(red[0], red[1]), fmaxf(red[2], red[3]));
  float p[4], s = 0.f, pr = 0.f;
#pragma unroll
  for (int t = 0; t < 4; ++t) {
    p[t] = __expf(v[t] - m);
    s += p[t];
    pr += p[t] * bv[tid + 256 * t];
  }
#pragma unroll
  for (int off = 32; off; off >>= 1) {
    s += __shfl_xor(s, off);
    pr += __shfl_xor(pr, off);
  }
  if (lane == 0) {
    red[4 + wv] = s;
    red[8 + wv] = pr;
  }
  __syncthreads();
  const float inv = 1.f / (red[4] + red[5] + red[6] + red[7]);
#pragma unroll
  for (int t = 0; t < 4; ++t)
    At[(size_t)j * 1024 + tid + 256 * t] = __float2bfloat16(p[t] * inv);
  if (tid == 0) rv[j] = (red[8] + red[9] + red[10] + red[11]) * inv;
}

// ---------------------------------------------------------------------------
extern "C" void kernel_launch(void* const* d_in, const int* in_sizes, int n_in,
                              void* d_out, int out_size, void* d_ws,
                              size_t ws_size, hipStream_t stream) {
  const float* x = (const float*)d_in[0];
  const float* Wq = (const float*)d_in[1];
  const float* bq = (const float*)d_in[2];
  const float* Wk = (const float*)d_in[3];
  const float* bk = (const float*)d_in[4];
  const float* Wv = (const float*)d_in[5];
  const float* bv = (const float*)d_in[6];
  (void)in_sizes;
  (void)n_in;
  (void)out_size;
  (void)ws_size;

  char* ws = (char*)d_ws;
  const size_t MB = 1ull << 20;
  bf16* xb = (bf16*)(ws);                // [8192][1024], 16MB
  bf16* xt = (bf16*)(ws + 16 * MB);      // [1024][8192], 16MB
  float* SpG = (float*)(ws + 32 * MB);   // [8][1024][1024] f32, 32MB
  bf16* Wkext = (bf16*)(ws + 64 * MB);   // [1024][2048] ([Wk|Wk]), 4MB
  bf16* Wqx2 = (bf16*)(ws + 68 * MB);    // [1024][2048] ([Wq|Wq]), 4MB
  bf16* Wvtb = (bf16*)(ws + 72 * MB);    // [1024][1024] (Wv^T), 2MB
  bf16* Gext = (bf16*)(ws + 74 * MB);    // [1024][2048], 4MB
  bf16* T1x = (bf16*)(ws + 78 * MB);     // [1024][2048] (T1 z-concat), 4MB
  float* Stp = (float*)(ws + 82 * MB);   // [2][1024][1024] f32, 8MB
  bf16* At = (bf16*)(ws + 90 * MB);      // [1024][1024], 2MB
  bf16* Ftb = (bf16*)(ws + 92 * MB);     // [1024][1024], 2MB
  float* uw = (float*)(ws + 94 * MB);           // [2048]
  float* rv = (float*)(ws + 94 * MB + 16384);   // [1024]
  float* part = (float*)(ws + 95 * MB);         // [128][1024] f32, 512KB

  // 1. x -> xb, xt, part; weights -> Wqx2, Wkext, Wvtb (one kernel)
  pre_all<<<dim3(16, 176), 256, 0, stream>>>(
      x, Wq, Wk, Wv, (unsigned short*)xb, (unsigned short*)xt, part,
      (unsigned short*)Wqx2, (unsigned short*)Wkext, (unsigned short*)Wvtb);
  // 2. uw = [Wq;Wk] . colsum(x)  (sv rebuilt per-block from part)
  sv_uw<<<128, 256, 0, stream>>>(part, Wq, Wk, uw);
  // 3. G = x^T x : NT(xt, xt), K=8192, split-K=8 -> f32 partials (512 blocks)
  gemm_nt<0, 0, 1, 0><<<dim3(8, 8, 8), 256, 0, stream>>>(
      xt, xt, nullptr, SpG, 1024, 1024, 8192, 1024, 1.0f);
  // 4. Gext = [bf16(G) | residual]
  gext_sum<<<1024, 256, 0, stream>>>(SpG, (unsigned short*)Gext);
  // 5. T1 = Wk*G: K=2048 split-K=2, bf16 col-concat -> T1x[1024][2048]
  gemm_nt<0, 1, 0, 1><<<dim3(8, 8, 2), 256, 0, stream>>>(
      Wkext, Gext, nullptr, T1x, 1024, 1024, 2048, 1024, 1.0f);
  // 6. St = T1x * Wqx2^T (K=2048), split-K=2 -> f32 partials (128 blocks)
  gemm_nt<0, 0, 0, 0><<<dim3(8, 8, 2), 256, 0, stream>>>(
      T1x, Wqx2, nullptr, Stp, 1024, 1024, 2048, 1024, 1.0f);
  // 7. atten^T = softmax(sum partials + corrections); r = atten^T.bv
  softmax_corr_r<<<1024, 256, 0, stream>>>(Stp, uw, bq, bk, bv, At, rv);
  // 8. F^T = NT(At, Wvt) -> bf16   (F = Wv^T atten)
  gemm_nt<0, 1, 1, 0><<<dim3(8, 8), 256, 0, stream>>>(
      At, Wvtb, nullptr, Ftb, 1024, 1024, 1024, 1024, 1.0f);
  // 9. out = x * F + 1*r^T : NT(xb, Ftb) + bias[col] -> f32 d_out
  gemm_nt<2, 0, 1, 0><<<dim3(8, 64), 256, 0, stream>>>(
      xb, Ftb, rv, d_out, 8192, 1024, 1024, 1024, 1.0f);
}

// Round 7
// 118.927 us; speedup vs baseline: 1.2181x; 1.0439x over previous
//
#include <hip/hip_runtime.h>
#include <hip/hip_bf16.h>
#include <stdint.h>

using bf16 = __hip_bfloat16;
typedef __attribute__((ext_vector_type(8))) short bf16x8;
typedef __attribute__((ext_vector_type(4))) float f32x4;

// ---------------------------------------------------------------------------
// helpers
// ---------------------------------------------------------------------------
__device__ __forceinline__ void gload_lds16(const void* g, void* l) {
  __builtin_amdgcn_global_load_lds(
      (__attribute__((address_space(1))) void*)(g),
      (__attribute__((address_space(3))) void*)(l), 16, 0, 0);
}

__device__ __forceinline__ unsigned short bf16_bits(float f) {
  bf16 b = __float2bfloat16(f);
  return *reinterpret_cast<unsigned short*>(&b);
}

__device__ __forceinline__ float b2f(unsigned short u) {
  union { unsigned int i; float f; } x;
  x.i = ((unsigned int)u) << 16;
  return x.f;
}

// ---------------------------------------------------------------------------
// pre_all: grid (16, 176).
//  y in [0,128):  x-tiles -> xb (bf16), xt (bf16 transpose), part (col sums)
//  y in [128,144): Wq stripes -> Wqx2 ([W|W] dup, ld 2048)
//  y in [144,160): Wk stripes -> Wkext ([W|W] dup, ld 2048)
//  y in [160,176): Wv stripes -> Wvtb (bf16 transpose)
// ---------------------------------------------------------------------------
__global__ __launch_bounds__(256) void pre_all(
    const float* __restrict__ x, const float* __restrict__ Wq,
    const float* __restrict__ Wk, const float* __restrict__ Wv,
    unsigned short* __restrict__ xb, unsigned short* __restrict__ xt,
    float* __restrict__ part, unsigned short* __restrict__ Wqx2,
    unsigned short* __restrict__ Wkext, unsigned short* __restrict__ Wvtb) {
  __shared__ unsigned short tile[64][79];
  __shared__ float cw[4][64];
  const int by = blockIdx.y;
  const int c0 = blockIdx.x * 64;
  const int tr = threadIdx.x >> 4;         // 0..15
  const int tc4 = (threadIdx.x & 15) * 4;  // 0,4,..,60

  if (by < 128) {
    const int r0 = by * 64;
    float ca0 = 0.f, ca1 = 0.f, ca2 = 0.f, ca3 = 0.f;
#pragma unroll
    for (int p = 0; p < 4; ++p) {
      const int r = p * 16 + tr;
      float4 f =
          *reinterpret_cast<const float4*>(x + (size_t)(r0 + r) * 1024 + c0 + tc4);
      unsigned short u0 = bf16_bits(f.x), u1 = bf16_bits(f.y);
      unsigned short u2 = bf16_bits(f.z), u3 = bf16_bits(f.w);
      ushort4 u = {u0, u1, u2, u3};
      *reinterpret_cast<ushort4*>(xb + (size_t)(r0 + r) * 1024 + c0 + tc4) = u;
      tile[r][tc4] = u0;
      tile[r][tc4 + 1] = u1;
      tile[r][tc4 + 2] = u2;
      tile[r][tc4 + 3] = u3;
      ca0 += f.x;
      ca1 += f.y;
      ca2 += f.z;
      ca3 += f.w;
    }
    ca0 += __shfl_xor(ca0, 16); ca0 += __shfl_xor(ca0, 32);
    ca1 += __shfl_xor(ca1, 16); ca1 += __shfl_xor(ca1, 32);
    ca2 += __shfl_xor(ca2, 16); ca2 += __shfl_xor(ca2, 32);
    ca3 += __shfl_xor(ca3, 16); ca3 += __shfl_xor(ca3, 32);
    const int lane = threadIdx.x & 63, wv = threadIdx.x >> 6;
    if (lane < 16) {
      cw[wv][lane * 4] = ca0;
      cw[wv][lane * 4 + 1] = ca1;
      cw[wv][lane * 4 + 2] = ca2;
      cw[wv][lane * 4 + 3] = ca3;
    }
    __syncthreads();
    if (threadIdx.x < 64) {
      float s = cw[0][threadIdx.x] + cw[1][threadIdx.x] + cw[2][threadIdx.x] +
                cw[3][threadIdx.x];
      part[(size_t)by * 1024 + c0 + threadIdx.x] = s;
    }
#pragma unroll
    for (int p = 0; p < 4; ++p) {
      const int c = p * 16 + tr;
      ushort4 u = {tile[tc4][c], tile[tc4 + 1][c], tile[tc4 + 2][c],
                   tile[tc4 + 3][c]};
      *reinterpret_cast<ushort4*>(xt + (size_t)(c0 + c) * 8192 + r0 + tc4) = u;
    }
  } else {
    const int w = by - 128;
    const int widx = w >> 4;          // 0=Wq,1=Wk,2=Wv
    const int r0 = (w & 15) * 64;
    if (widx < 2) {
      const float* W = (widx == 0) ? Wq : Wk;
      unsigned short* out = (widx == 0) ? Wqx2 : Wkext;
#pragma unroll
      for (int p = 0; p < 4; ++p) {
        const int r = r0 + p * 16 + tr;
        float4 f =
            *reinterpret_cast<const float4*>(W + (size_t)r * 1024 + c0 + tc4);
        ushort4 u = {bf16_bits(f.x), bf16_bits(f.y), bf16_bits(f.z),
                     bf16_bits(f.w)};
        *reinterpret_cast<ushort4*>(out + (size_t)r * 2048 + c0 + tc4) = u;
        *reinterpret_cast<ushort4*>(out + (size_t)r * 2048 + 1024 + c0 + tc4) = u;
      }
    } else {
#pragma unroll
      for (int p = 0; p < 4; ++p) {
        const int r = p * 16 + tr;
        float4 f = *reinterpret_cast<const float4*>(Wv + (size_t)(r0 + r) * 1024 +
                                                    c0 + tc4);
        tile[r][tc4] = bf16_bits(f.x);
        tile[r][tc4 + 1] = bf16_bits(f.y);
        tile[r][tc4 + 2] = bf16_bits(f.z);
        tile[r][tc4 + 3] = bf16_bits(f.w);
      }
      __syncthreads();
#pragma unroll
      for (int p = 0; p < 4; ++p) {
        const int c = p * 16 + tr;
        ushort4 u = {tile[tc4][c], tile[tc4 + 1][c], tile[tc4 + 2][c],
                     tile[tc4 + 3][c]};
        *reinterpret_cast<ushort4*>(Wvtb + (size_t)(c0 + c) * 1024 + r0 + tc4) = u;
      }
    }
  }
}

// ---------------------------------------------------------------------------
// NT GEMM, 2-phase double-buffered (64KB LDS, 2 blocks/CU): for big GEMMs.
// 128x128 tile, BK=64, 4 waves, T2 swizzle via pre-swizzled global source.
// BIAS_MODE: 0 none, 2 bias[col]. OUT_BF16: 1 -> bf16 C. XCD_SWZ: T1 swizzle.
// CONCAT: 1 -> partials column-concatenated C[row][z*N+col], ld gridDim.z*N.
// ---------------------------------------------------------------------------
template <int BIAS_MODE, int OUT_BF16, int XCD_SWZ, int CONCAT>
__global__ __launch_bounds__(256, 2) void gemm_nt(
    const bf16* __restrict__ A, const bf16* __restrict__ B,
    const float* __restrict__ bias, void* __restrict__ Cout, int M, int N,
    int K, int kChunk, float scale) {
  __shared__ __align__(128) char lds[65536];  // A: [2][16KB] @0, B: @32768
  const int tid = threadIdx.x;
  const int lane = tid & 63;
  const int wv = tid >> 6;
  const int wm = wv >> 1, wn = wv & 1;

  int mt, nt;
  if (XCD_SWZ) {
    int lin = blockIdx.y * gridDim.x + blockIdx.x;
    int cpx = (gridDim.x * gridDim.y) >> 3;  // nwg % 8 == 0 required
    int swz = (lin & 7) * cpx + (lin >> 3);
    nt = swz % gridDim.x;
    mt = swz / gridDim.x;
  } else {
    nt = blockIdx.x;
    mt = blockIdx.y;
  }
  const int m0 = mt * 128, n0 = nt * 128;
  const int kBegin = blockIdx.z * kChunk;

  const char* srcA[4];
  const char* srcB[4];
  int dstOff[4];
#pragma unroll
  for (int t = 0; t < 4; ++t) {
    int o = wv * 4096 + t * 1024 + lane * 16;  // linear LDS byte offset
    int row = o >> 7;                          // tile row (128B per row)
    int gcb = (o & 127) ^ ((row & 7) << 4);    // inverse-swizzled global col
    srcA[t] = (const char*)A + ((size_t)(m0 + row) * K + kBegin) * 2 + gcb;
    srcB[t] = (const char*)B + ((size_t)(n0 + row) * K + kBegin) * 2 + gcb;
    dstOff[t] = wv * 4096 + t * 1024;
  }

  const int xorv = (lane & 7) << 4;
  const int rowOff = (lane & 15) * 128;
  const int colHi = (lane >> 4) << 4;

  // prologue: stage tile 0 into buf 0
#pragma unroll
  for (int t = 0; t < 4; ++t) gload_lds16(srcA[t], lds + dstOff[t]);
#pragma unroll
  for (int t = 0; t < 4; ++t) gload_lds16(srcB[t], lds + 32768 + dstOff[t]);
#pragma unroll
  for (int t = 0; t < 4; ++t) {
    srcA[t] += 128;
    srcB[t] += 128;
  }
  __syncthreads();

  f32x4 acc[4][4] = {};
  const int nk = kChunk >> 6;
  int cur = 0;
  for (int kt = 0; kt < nk; ++kt) {
    if (kt + 1 < nk) {  // prefetch next tile into the other buffer
      const int nb = (cur ^ 1) * 16384;
#pragma unroll
      for (int t = 0; t < 4; ++t) gload_lds16(srcA[t], lds + nb + dstOff[t]);
#pragma unroll
      for (int t = 0; t < 4; ++t)
        gload_lds16(srcB[t], lds + 32768 + nb + dstOff[t]);
#pragma unroll
      for (int t = 0; t < 4; ++t) {
        srcA[t] += 128;
        srcB[t] += 128;
      }
    }
    const char* baseA = lds + cur * 16384;
    const char* baseB = lds + 32768 + cur * 16384;
#pragma unroll
    for (int h = 0; h < 2; ++h) {
      const int kk64 = h * 64;
      bf16x8 af[4], bfr[4];
#pragma unroll
      for (int f = 0; f < 4; ++f)
        af[f] = *reinterpret_cast<const bf16x8*>(
            baseA + ((wm * 64 + f * 16) * 128) + rowOff + ((kk64 + colHi) ^ xorv));
#pragma unroll
      for (int f = 0; f < 4; ++f)
        bfr[f] = *reinterpret_cast<const bf16x8*>(
            baseB + ((wn * 64 + f * 16) * 128) + rowOff + ((kk64 + colHi) ^ xorv));
      __builtin_amdgcn_s_setprio(1);
#pragma unroll
      for (int m = 0; m < 4; ++m)
#pragma unroll
        for (int n = 0; n < 4; ++n)
          acc[m][n] = __builtin_amdgcn_mfma_f32_16x16x32_bf16(af[m], bfr[n],
                                                              acc[m][n], 0, 0, 0);
      __builtin_amdgcn_s_setprio(0);
    }
    __syncthreads();  // staged loads drained; all waves done reading cur
    cur ^= 1;
  }

  // epilogue: C/D layout col=lane&15, row=(lane>>4)*4+r (guide §3, m89)
  const int ldC = CONCAT ? (int)(gridDim.z * N) : N;
  const int cOff = CONCAT ? (int)(blockIdx.z * N) : 0;
  char* Cbase = (char*)Cout;
  if (!CONCAT) Cbase += (size_t)blockIdx.z * M * N * (OUT_BF16 ? 2 : 4);
#pragma unroll
  for (int m = 0; m < 4; ++m) {
    const int grow = m0 + wm * 64 + m * 16 + ((lane >> 4) << 2);
#pragma unroll
    for (int n = 0; n < 4; ++n) {
      const int gcol = n0 + wn * 64 + n * 16 + (lane & 15);
#pragma unroll
      for (int r = 0; r < 4; ++r) {
        float v = acc[m][n][r] * scale;
        if (BIAS_MODE == 2) v += bias[gcol];
        if (OUT_BF16)
          ((bf16*)Cbase)[(size_t)(grow + r) * ldC + cOff + gcol] =
              __float2bfloat16(v);
        else
          ((float*)Cbase)[(size_t)(grow + r) * ldC + cOff + gcol] = v;
      }
    }
  }
}

// ---------------------------------------------------------------------------
// NT GEMM, 64x64 tile, single-buffered 16KB LDS, high occupancy (256,4):
// for small latency-bound GEMMs. Same swizzle/fragment addressing as 128².
// 4 waves each own a 32x32 quadrant (2x2 fragments).
// ---------------------------------------------------------------------------
template <int BIAS_MODE, int OUT_BF16, int XCD_SWZ, int CONCAT>
__global__ __launch_bounds__(256, 4) void gemm_nt64(
    const bf16* __restrict__ A, const bf16* __restrict__ B,
    const float* __restrict__ bias, void* __restrict__ Cout, int M, int N,
    int K, int kChunk, float scale) {
  __shared__ __align__(128) char lds[16384];  // A 8KB @0, B @8192
  const int tid = threadIdx.x;
  const int lane = tid & 63;
  const int wv = tid >> 6;
  const int wm = wv >> 1, wn = wv & 1;

  int mt, nt;
  if (XCD_SWZ) {
    int lin = blockIdx.y * gridDim.x + blockIdx.x;
    int cpx = (gridDim.x * gridDim.y) >> 3;  // nwg % 8 == 0 required
    int swz = (lin & 7) * cpx + (lin >> 3);
    nt = swz % gridDim.x;
    mt = swz / gridDim.x;
  } else {
    nt = blockIdx.x;
    mt = blockIdx.y;
  }
  const int m0 = mt * 64, n0 = nt * 64;
  const int kBegin = blockIdx.z * kChunk;

  const char* srcA[2];
  const char* srcB[2];
  int dstOff[2];
#pragma unroll
  for (int t = 0; t < 2; ++t) {
    int o = wv * 2048 + t * 1024 + lane * 16;  // linear LDS byte offset
    int row = o >> 7;                          // tile row (128B per row)
    int gcb = (o & 127) ^ ((row & 7) << 4);    // inverse-swizzled global col
    srcA[t] = (const char*)A + ((size_t)(m0 + row) * K + kBegin) * 2 + gcb;
    srcB[t] = (const char*)B + ((size_t)(n0 + row) * K + kBegin) * 2 + gcb;
    dstOff[t] = wv * 2048 + t * 1024;
  }

  const int xorv = (lane & 7) << 4;
  const int rowOff = (lane & 15) * 128;
  const int colHi = (lane >> 4) << 4;

  f32x4 acc[2][2] = {};
  const int nk = kChunk >> 6;
  for (int kt = 0; kt < nk; ++kt) {
#pragma unroll
    for (int t = 0; t < 2; ++t) gload_lds16(srcA[t], lds + dstOff[t]);
#pragma unroll
    for (int t = 0; t < 2; ++t) gload_lds16(srcB[t], lds + 8192 + dstOff[t]);
#pragma unroll
    for (int t = 0; t < 2; ++t) {
      srcA[t] += 128;
      srcB[t] += 128;
    }
    __syncthreads();
#pragma unroll
    for (int h = 0; h < 2; ++h) {
      const int kk64 = h * 64;
      bf16x8 af[2], bfr[2];
#pragma unroll
      for (int f = 0; f < 2; ++f)
        af[f] = *reinterpret_cast<const bf16x8*>(
            lds + ((wm * 32 + f * 16) * 128) + rowOff + ((kk64 + colHi) ^ xorv));
#pragma unroll
      for (int f = 0; f < 2; ++f)
        bfr[f] = *reinterpret_cast<const bf16x8*>(
            lds + 8192 + ((wn * 32 + f * 16) * 128) + rowOff +
            ((kk64 + colHi) ^ xorv));
      __builtin_amdgcn_s_setprio(1);
#pragma unroll
      for (int m = 0; m < 2; ++m)
#pragma unroll
        for (int n = 0; n < 2; ++n)
          acc[m][n] = __builtin_amdgcn_mfma_f32_16x16x32_bf16(af[m], bfr[n],
                                                              acc[m][n], 0, 0, 0);
      __builtin_amdgcn_s_setprio(0);
    }
    __syncthreads();
  }

  const int ldC = CONCAT ? (int)(gridDim.z * N) : N;
  const int cOff = CONCAT ? (int)(blockIdx.z * N) : 0;
  char* Cbase = (char*)Cout;
  if (!CONCAT) Cbase += (size_t)blockIdx.z * M * N * (OUT_BF16 ? 2 : 4);
#pragma unroll
  for (int m = 0; m < 2; ++m) {
    const int grow = m0 + wm * 32 + m * 16 + ((lane >> 4) << 2);
#pragma unroll
    for (int n = 0; n < 2; ++n) {
      const int gcol = n0 + wn * 32 + n * 16 + (lane & 15);
#pragma unroll
      for (int r = 0; r < 4; ++r) {
        float v = acc[m][n][r] * scale;
        if (BIAS_MODE == 2) v += bias[gcol];
        if (OUT_BF16)
          ((bf16*)Cbase)[(size_t)(grow + r) * ldC + cOff + gcol] =
              __float2bfloat16(v);
        else
          ((float*)Cbase)[(size_t)(grow + r) * ldC + cOff + gcol] = v;
      }
    }
  }
}

// ---------------------------------------------------------------------------
// merged node: blocks [0,1024): sum 8 split-K partials of G = x^T x, emit
// Gext = [bf16(G) | bf16(residual)]. blocks [1024,1152): sv_uw — rebuild
// sv = colsum(x) from part, then 16 rows of uw = [Wq;Wk] . sv per block.
// ---------------------------------------------------------------------------
__global__ __launch_bounds__(256) void gext_svuw(
    const float* __restrict__ Sp, unsigned short* __restrict__ Gext,
    const float* __restrict__ part, const float* __restrict__ Wq,
    const float* __restrict__ Wk, float* __restrict__ uw) {
  __shared__ float svl[1024];
  const int tid = threadIdx.x;
  if (blockIdx.x < 1024) {
    const int k = blockIdx.x;
    const int c4 = tid * 4;
    float g[4] = {0.f, 0.f, 0.f, 0.f};
#pragma unroll
    for (int z = 0; z < 8; ++z) {
      float4 f = *reinterpret_cast<const float4*>(Sp + ((size_t)z << 20) +
                                                  (size_t)k * 1024 + c4);
      g[0] += f.x;
      g[1] += f.y;
      g[2] += f.z;
      g[3] += f.w;
    }
    ushort4 hi, lo;
    unsigned short* h = &hi.x;
    unsigned short* l = &lo.x;
#pragma unroll
    for (int q = 0; q < 4; ++q) {
      unsigned short b = bf16_bits(g[q]);
      h[q] = b;
      l[q] = bf16_bits(g[q] - b2f(b));
    }
    *reinterpret_cast<ushort4*>(Gext + (size_t)k * 2048 + c4) = hi;
    *reinterpret_cast<ushort4*>(Gext + (size_t)k * 2048 + 1024 + c4) = lo;
  } else {
    float4 a = {0.f, 0.f, 0.f, 0.f};
    for (int p = 0; p < 128; ++p) {
      float4 f =
          *reinterpret_cast<const float4*>(part + (size_t)p * 1024 + tid * 4);
      a.x += f.x;
      a.y += f.y;
      a.z += f.z;
      a.w += f.w;
    }
    *reinterpret_cast<float4*>(svl + tid * 4) = a;
    __syncthreads();

    const int lane = tid & 63, wv = tid >> 6;
    const int lane16 = lane & 15, rsub = lane >> 4;
    const int row = (blockIdx.x - 1024) * 16 + wv * 4 + rsub;
    const float* W = (row < 1024) ? (Wq + (size_t)row * 1024)
                                  : (Wk + (size_t)(row - 1024) * 1024);
    float acc = 0.f;
#pragma unroll
    for (int q = 0; q < 16; ++q) {
      const int c = (lane16 + q * 16) * 4;
      float4 wv4 = *reinterpret_cast<const float4*>(W + c);
      float4 s4 = *reinterpret_cast<const float4*>(svl + c);
      acc += wv4.x * s4.x + wv4.y * s4.y + wv4.z * s4.z + wv4.w * s4.w;
    }
#pragma unroll
    for (int off = 1; off < 16; off <<= 1) acc += __shfl_xor(acc, off);
    if (lane16 == 0) uw[row] = acc;
  }
}

// ---------------------------------------------------------------------------
// row-softmax over 2 St split-K partials with rank-1 bias corrections and
// fused r[j] = atten[:,j].bv
// ---------------------------------------------------------------------------
__global__ __launch_bounds__(256) void softmax_corr_r(
    const float* __restrict__ Stp, const float* __restrict__ uw,
    const float* __restrict__ bq, const float* __restrict__ bk,
    const float* __restrict__ bv, bf16* __restrict__ At,
    float* __restrict__ rv) {
  const int j = blockIdx.x;
  const int tid = threadIdx.x;
  const int lane = tid & 63, wv = tid >> 6;
  const float a1 = bk[j];
  const float a2 = uw[1024 + j] + 8192.0f * a1;
  const float norm = 0.03125f;  // 1/sqrt(1024)
  float v[4];
#pragma unroll
  for (int t = 0; t < 4; ++t) {
    const int i = tid + 256 * t;
    float s = Stp[(size_t)j * 1024 + i] + Stp[(1ull << 20) + (size_t)j * 1024 + i];
    v[t] = norm * (s + a1 * uw[i] + a2 * bq[i]);
  }
  float m = fmaxf(fmaxf(v[0], v[1]), fmaxf(v[2], v[3]));
#pragma unroll
  for (int off = 32; off; off >>= 1) m = fmaxf(m, __shfl_xor(m, off));
  __shared__ float red[12];
  if (lane == 0) red[wv] = m;
  __syncthreads();
  m = fmaxf(fmaxf(red[0], red[1]), fmaxf(red[2], red[3]));
  float p[4], s = 0.f, pr = 0.f;
#pragma unroll
  for (int t = 0; t < 4; ++t) {
    p[t] = __expf(v[t] - m);
    s += p[t];
    pr += p[t] * bv[tid + 256 * t];
  }
#pragma unroll
  for (int off = 32; off; off >>= 1) {
    s += __shfl_xor(s, off);
    pr += __shfl_xor(pr, off);
  }
  if (lane == 0) {
    red[4 + wv] = s;
    red[8 + wv] = pr;
  }
  __syncthreads();
  const float inv = 1.f / (red[4] + red[5] + red[6] + red[7]);
#pragma unroll
  for (int t = 0; t < 4; ++t)
    At[(size_t)j * 1024 + tid + 256 * t] = __float2bfloat16(p[t] * inv);
  if (tid == 0) rv[j] = (red[8] + red[9] + red[10] + red[11]) * inv;
}

// ---------------------------------------------------------------------------
extern "C" void kernel_launch(void* const* d_in, const int* in_sizes, int n_in,
                              void* d_out, int out_size, void* d_ws,
                              size_t ws_size, hipStream_t stream) {
  const float* x = (const float*)d_in[0];
  const float* Wq = (const float*)d_in[1];
  const float* bq = (const float*)d_in[2];
  const float* Wk = (const float*)d_in[3];
  const float* bk = (const float*)d_in[4];
  const float* Wv = (const float*)d_in[5];
  const float* bv = (const float*)d_in[6];
  (void)in_sizes;
  (void)n_in;
  (void)out_size;
  (void)ws_size;

  char* ws = (char*)d_ws;
  const size_t MB = 1ull << 20;
  bf16* xb = (bf16*)(ws);                // [8192][1024], 16MB
  bf16* xt = (bf16*)(ws + 16 * MB);      // [1024][8192], 16MB
  float* SpG = (float*)(ws + 32 * MB);   // [8][1024][1024] f32, 32MB
  bf16* Wkext = (bf16*)(ws + 64 * MB);   // [1024][2048] ([Wk|Wk]), 4MB
  bf16* Wqx2 = (bf16*)(ws + 68 * MB);    // [1024][2048] ([Wq|Wq]), 4MB
  bf16* Wvtb = (bf16*)(ws + 72 * MB);    // [1024][1024] (Wv^T), 2MB
  bf16* Gext = (bf16*)(ws + 74 * MB);    // [1024][2048], 4MB
  bf16* T1x = (bf16*)(ws + 78 * MB);     // [1024][2048] (T1 z-concat), 4MB
  float* Stp = (float*)(ws + 82 * MB);   // [2][1024][1024] f32, 8MB
  bf16* At = (bf16*)(ws + 90 * MB);      // [1024][1024], 2MB
  bf16* Ftb = (bf16*)(ws + 92 * MB);     // [1024][1024], 2MB
  float* uw = (float*)(ws + 94 * MB);           // [2048]
  float* rv = (float*)(ws + 94 * MB + 16384);   // [1024]
  float* part = (float*)(ws + 95 * MB);         // [128][1024] f32, 512KB

  // 1. x -> xb, xt, part; weights -> Wqx2, Wkext, Wvtb (one kernel)
  pre_all<<<dim3(16, 176), 256, 0, stream>>>(
      x, Wq, Wk, Wv, (unsigned short*)xb, (unsigned short*)xt, part,
      (unsigned short*)Wqx2, (unsigned short*)Wkext, (unsigned short*)Wvtb);
  // 2. G = x^T x : NT(xt, xt), K=8192, split-K=8 -> f32 partials (512 blocks)
  gemm_nt<0, 0, 1, 0><<<dim3(8, 8, 8), 256, 0, stream>>>(
      xt, xt, nullptr, SpG, 1024, 1024, 8192, 1024, 1.0f);
  // 3. Gext = [bf16(G) | residual]  +  uw = [Wq;Wk].colsum(x)  (one node)
  gext_svuw<<<1152, 256, 0, stream>>>(SpG, (unsigned short*)Gext, part, Wq, Wk,
                                      uw);
  // 4. T1 = Wk*G: K=2048 split-K=2, bf16 col-concat -> T1x[1024][2048]
  gemm_nt64<0, 1, 1, 1><<<dim3(16, 16, 2), 256, 0, stream>>>(
      Wkext, Gext, nullptr, T1x, 1024, 1024, 2048, 1024, 1.0f);
  // 5. St = T1x * Wqx2^T (K=2048), split-K=2 -> f32 partials (512 blocks)
  gemm_nt64<0, 0, 1, 0><<<dim3(16, 16, 2), 256, 0, stream>>>(
      T1x, Wqx2, nullptr, Stp, 1024, 1024, 2048, 1024, 1.0f);
  // 6. atten^T = softmax(sum partials + corrections); r = atten^T.bv
  softmax_corr_r<<<1024, 256, 0, stream>>>(Stp, uw, bq, bk, bv, At, rv);
  // 7. F^T = NT(At, Wvt) -> bf16   (F = Wv^T atten)  (256 blocks)
  gemm_nt64<0, 1, 1, 0><<<dim3(16, 16), 256, 0, stream>>>(
      At, Wvtb, nullptr, Ftb, 1024, 1024, 1024, 1024, 1.0f);
  // 8. out = x * F + 1*r^T : NT(xb, Ftb) + bias[col] -> f32 d_out
  gemm_nt<2, 0, 1, 0><<<dim3(8, 64), 256, 0, stream>>>(
      xb, Ftb, rv, d_out, 8192, 1024, 1024, 1024, 1.0f);
}

// Round 8
// 108.317 us; speedup vs baseline: 1.3374x; 1.0980x over previous
//
#include <hip/hip_runtime.h>
#include <hip/hip_bf16.h>
#include <stdint.h>

using bf16 = __hip_bfloat16;
typedef __attribute__((ext_vector_type(8))) short bf16x8;
typedef __attribute__((ext_vector_type(4))) float f32x4;

// ---------------------------------------------------------------------------
// helpers
// ---------------------------------------------------------------------------
__device__ __forceinline__ void gload_lds16(const void* g, void* l) {
  __builtin_amdgcn_global_load_lds(
      (__attribute__((address_space(1))) void*)(g),
      (__attribute__((address_space(3))) void*)(l), 16, 0, 0);
}

__device__ __forceinline__ unsigned short bf16_bits(float f) {
  bf16 b = __float2bfloat16(f);
  return *reinterpret_cast<unsigned short*>(&b);
}

__device__ __forceinline__ float b2f(unsigned short u) {
  union { unsigned int i; float f; } x;
  x.i = ((unsigned int)u) << 16;
  return x.f;
}

// ---------------------------------------------------------------------------
// pre_all: grid (16, 176).
//  y in [0,128):  x-tiles -> xb (bf16), xt (bf16 transpose), part (col sums)
//  y in [128,144): Wq stripes -> Wqx2 ([W|W] dup, ld 2048)
//  y in [144,160): Wk stripes -> Wkext ([W|W] dup, ld 2048)
//  y in [160,176): Wv stripes -> Wvtb (bf16 transpose)
// ---------------------------------------------------------------------------
__global__ __launch_bounds__(256) void pre_all(
    const float* __restrict__ x, const float* __restrict__ Wq,
    const float* __restrict__ Wk, const float* __restrict__ Wv,
    unsigned short* __restrict__ xb, unsigned short* __restrict__ xt,
    float* __restrict__ part, unsigned short* __restrict__ Wqx2,
    unsigned short* __restrict__ Wkext, unsigned short* __restrict__ Wvtb) {
  __shared__ unsigned short tile[64][79];
  __shared__ float cw[4][64];
  const int by = blockIdx.y;
  const int c0 = blockIdx.x * 64;
  const int tr = threadIdx.x >> 4;         // 0..15
  const int tc4 = (threadIdx.x & 15) * 4;  // 0,4,..,60

  if (by < 128) {
    const int r0 = by * 64;
    float ca0 = 0.f, ca1 = 0.f, ca2 = 0.f, ca3 = 0.f;
#pragma unroll
    for (int p = 0; p < 4; ++p) {
      const int r = p * 16 + tr;
      float4 f =
          *reinterpret_cast<const float4*>(x + (size_t)(r0 + r) * 1024 + c0 + tc4);
      unsigned short u0 = bf16_bits(f.x), u1 = bf16_bits(f.y);
      unsigned short u2 = bf16_bits(f.z), u3 = bf16_bits(f.w);
      ushort4 u = {u0, u1, u2, u3};
      *reinterpret_cast<ushort4*>(xb + (size_t)(r0 + r) * 1024 + c0 + tc4) = u;
      tile[r][tc4] = u0;
      tile[r][tc4 + 1] = u1;
      tile[r][tc4 + 2] = u2;
      tile[r][tc4 + 3] = u3;
      ca0 += f.x;
      ca1 += f.y;
      ca2 += f.z;
      ca3 += f.w;
    }
    ca0 += __shfl_xor(ca0, 16); ca0 += __shfl_xor(ca0, 32);
    ca1 += __shfl_xor(ca1, 16); ca1 += __shfl_xor(ca1, 32);
    ca2 += __shfl_xor(ca2, 16); ca2 += __shfl_xor(ca2, 32);
    ca3 += __shfl_xor(ca3, 16); ca3 += __shfl_xor(ca3, 32);
    const int lane = threadIdx.x & 63, wv = threadIdx.x >> 6;
    if (lane < 16) {
      cw[wv][lane * 4] = ca0;
      cw[wv][lane * 4 + 1] = ca1;
      cw[wv][lane * 4 + 2] = ca2;
      cw[wv][lane * 4 + 3] = ca3;
    }
    __syncthreads();
    if (threadIdx.x < 64) {
      float s = cw[0][threadIdx.x] + cw[1][threadIdx.x] + cw[2][threadIdx.x] +
                cw[3][threadIdx.x];
      part[(size_t)by * 1024 + c0 + threadIdx.x] = s;
    }
#pragma unroll
    for (int p = 0; p < 4; ++p) {
      const int c = p * 16 + tr;
      ushort4 u = {tile[tc4][c], tile[tc4 + 1][c], tile[tc4 + 2][c],
                   tile[tc4 + 3][c]};
      *reinterpret_cast<ushort4*>(xt + (size_t)(c0 + c) * 8192 + r0 + tc4) = u;
    }
  } else {
    const int w = by - 128;
    const int widx = w >> 4;          // 0=Wq,1=Wk,2=Wv
    const int r0 = (w & 15) * 64;
    if (widx < 2) {
      const float* W = (widx == 0) ? Wq : Wk;
      unsigned short* out = (widx == 0) ? Wqx2 : Wkext;
#pragma unroll
      for (int p = 0; p < 4; ++p) {
        const int r = r0 + p * 16 + tr;
        float4 f =
            *reinterpret_cast<const float4*>(W + (size_t)r * 1024 + c0 + tc4);
        ushort4 u = {bf16_bits(f.x), bf16_bits(f.y), bf16_bits(f.z),
                     bf16_bits(f.w)};
        *reinterpret_cast<ushort4*>(out + (size_t)r * 2048 + c0 + tc4) = u;
        *reinterpret_cast<ushort4*>(out + (size_t)r * 2048 + 1024 + c0 + tc4) = u;
      }
    } else {
#pragma unroll
      for (int p = 0; p < 4; ++p) {
        const int r = p * 16 + tr;
        float4 f = *reinterpret_cast<const float4*>(Wv + (size_t)(r0 + r) * 1024 +
                                                    c0 + tc4);
        tile[r][tc4] = bf16_bits(f.x);
        tile[r][tc4 + 1] = bf16_bits(f.y);
        tile[r][tc4 + 2] = bf16_bits(f.z);
        tile[r][tc4 + 3] = bf16_bits(f.w);
      }
      __syncthreads();
#pragma unroll
      for (int p = 0; p < 4; ++p) {
        const int c = p * 16 + tr;
        ushort4 u = {tile[tc4][c], tile[tc4 + 1][c], tile[tc4 + 2][c],
                     tile[tc4 + 3][c]};
        *reinterpret_cast<ushort4*>(Wvtb + (size_t)(c0 + c) * 1024 + r0 + tc4) = u;
      }
    }
  }
}

// ---------------------------------------------------------------------------
// NT GEMM, 2-phase double-buffered (64KB LDS, 2 blocks/CU): for big GEMMs.
// 128x128 tile, BK=64, 4 waves, T2 swizzle via pre-swizzled global source.
// BIAS_MODE: 0 none, 2 bias[col]. OUT_BF16: 1 -> bf16 C. XCD_SWZ: T1 swizzle.
// CONCAT: 1 -> partials column-concatenated C[row][z*N+col], ld gridDim.z*N.
// TRI: 1 -> symmetric-triangle mode (A==B): grid (288,1,1);
//   z = lin&7 (one K-chunk per XCD), p = lin>>3 unranked to (mt,nt), mt>=nt.
//   Only lower-triangle 128-tiles computed; partial written at z*M*N.
// ---------------------------------------------------------------------------
template <int BIAS_MODE, int OUT_BF16, int XCD_SWZ, int CONCAT, int TRI>
__global__ __launch_bounds__(256, 2) void gemm_nt(
    const bf16* __restrict__ A, const bf16* __restrict__ B,
    const float* __restrict__ bias, void* __restrict__ Cout, int M, int N,
    int K, int kChunk, float scale) {
  __shared__ __align__(128) char lds[65536];  // A: [2][16KB] @0, B: @32768
  const int tid = threadIdx.x;
  const int lane = tid & 63;
  const int wv = tid >> 6;
  const int wm = wv >> 1, wn = wv & 1;

  int mt, nt, zz;
  if (TRI) {
    const int lin = blockIdx.x;
    zz = lin & 7;        // HW: block lin runs on XCD lin%8 -> z-chunk per XCD
    const int p = lin >> 3;  // 0..35 triangle pair
    int ii = 0;
    while ((ii + 1) * (ii + 2) / 2 <= p) ++ii;
    mt = ii;
    nt = p - ii * (ii + 1) / 2;
  } else if (XCD_SWZ) {
    int lin = blockIdx.y * gridDim.x + blockIdx.x;
    int cpx = (gridDim.x * gridDim.y) >> 3;  // nwg % 8 == 0 required
    int swz = (lin & 7) * cpx + (lin >> 3);
    nt = swz % gridDim.x;
    mt = swz / gridDim.x;
    zz = blockIdx.z;
  } else {
    nt = blockIdx.x;
    mt = blockIdx.y;
    zz = blockIdx.z;
  }
  const int m0 = mt * 128, n0 = nt * 128;
  const int kBegin = zz * kChunk;

  const char* srcA[4];
  const char* srcB[4];
  int dstOff[4];
#pragma unroll
  for (int t = 0; t < 4; ++t) {
    int o = wv * 4096 + t * 1024 + lane * 16;  // linear LDS byte offset
    int row = o >> 7;                          // tile row (128B per row)
    int gcb = (o & 127) ^ ((row & 7) << 4);    // inverse-swizzled global col
    srcA[t] = (const char*)A + ((size_t)(m0 + row) * K + kBegin) * 2 + gcb;
    srcB[t] = (const char*)B + ((size_t)(n0 + row) * K + kBegin) * 2 + gcb;
    dstOff[t] = wv * 4096 + t * 1024;
  }

  const int xorv = (lane & 7) << 4;
  const int rowOff = (lane & 15) * 128;
  const int colHi = (lane >> 4) << 4;

  // prologue: stage tile 0 into buf 0
#pragma unroll
  for (int t = 0; t < 4; ++t) gload_lds16(srcA[t], lds + dstOff[t]);
#pragma unroll
  for (int t = 0; t < 4; ++t) gload_lds16(srcB[t], lds + 32768 + dstOff[t]);
#pragma unroll
  for (int t = 0; t < 4; ++t) {
    srcA[t] += 128;
    srcB[t] += 128;
  }
  __syncthreads();

  f32x4 acc[4][4] = {};
  const int nk = kChunk >> 6;
  int cur = 0;
  for (int kt = 0; kt < nk; ++kt) {
    if (kt + 1 < nk) {  // prefetch next tile into the other buffer
      const int nb = (cur ^ 1) * 16384;
#pragma unroll
      for (int t = 0; t < 4; ++t) gload_lds16(srcA[t], lds + nb + dstOff[t]);
#pragma unroll
      for (int t = 0; t < 4; ++t)
        gload_lds16(srcB[t], lds + 32768 + nb + dstOff[t]);
#pragma unroll
      for (int t = 0; t < 4; ++t) {
        srcA[t] += 128;
        srcB[t] += 128;
      }
    }
    const char* baseA = lds + cur * 16384;
    const char* baseB = lds + 32768 + cur * 16384;
#pragma unroll
    for (int h = 0; h < 2; ++h) {
      const int kk64 = h * 64;
      bf16x8 af[4], bfr[4];
#pragma unroll
      for (int f = 0; f < 4; ++f)
        af[f] = *reinterpret_cast<const bf16x8*>(
            baseA + ((wm * 64 + f * 16) * 128) + rowOff + ((kk64 + colHi) ^ xorv));
#pragma unroll
      for (int f = 0; f < 4; ++f)
        bfr[f] = *reinterpret_cast<const bf16x8*>(
            baseB + ((wn * 64 + f * 16) * 128) + rowOff + ((kk64 + colHi) ^ xorv));
      __builtin_amdgcn_s_setprio(1);
#pragma unroll
      for (int m = 0; m < 4; ++m)
#pragma unroll
        for (int n = 0; n < 4; ++n)
          acc[m][n] = __builtin_amdgcn_mfma_f32_16x16x32_bf16(af[m], bfr[n],
                                                              acc[m][n], 0, 0, 0);
      __builtin_amdgcn_s_setprio(0);
    }
    __syncthreads();  // staged loads drained; all waves done reading cur
    cur ^= 1;
  }

  // epilogue: C/D layout col=lane&15, row=(lane>>4)*4+r (guide §3, m89)
  const int ldC = CONCAT ? (int)(gridDim.z * N) : N;
  const int cOff = CONCAT ? (int)(zz * N) : 0;
  char* Cbase = (char*)Cout;
  if (!CONCAT) Cbase += (size_t)zz * M * N * (OUT_BF16 ? 2 : 4);
#pragma unroll
  for (int m = 0; m < 4; ++m) {
    const int grow = m0 + wm * 64 + m * 16 + ((lane >> 4) << 2);
#pragma unroll
    for (int n = 0; n < 4; ++n) {
      const int gcol = n0 + wn * 64 + n * 16 + (lane & 15);
#pragma unroll
      for (int r = 0; r < 4; ++r) {
        float v = acc[m][n][r] * scale;
        if (BIAS_MODE == 2) v += bias[gcol];
        if (OUT_BF16)
          ((bf16*)Cbase)[(size_t)(grow + r) * ldC + cOff + gcol] =
              __float2bfloat16(v);
        else
          ((float*)Cbase)[(size_t)(grow + r) * ldC + cOff + gcol] = v;
      }
    }
  }
}

// ---------------------------------------------------------------------------
// NT GEMM, 64x64 tile, single-buffered 16KB LDS, high occupancy (256,4):
// for small latency-bound GEMMs. 4 waves each own a 32x32 quadrant.
// ---------------------------------------------------------------------------
template <int BIAS_MODE, int OUT_BF16, int XCD_SWZ, int CONCAT>
__global__ __launch_bounds__(256, 4) void gemm_nt64(
    const bf16* __restrict__ A, const bf16* __restrict__ B,
    const float* __restrict__ bias, void* __restrict__ Cout, int M, int N,
    int K, int kChunk, float scale) {
  __shared__ __align__(128) char lds[16384];  // A 8KB @0, B @8192
  const int tid = threadIdx.x;
  const int lane = tid & 63;
  const int wv = tid >> 6;
  const int wm = wv >> 1, wn = wv & 1;

  int mt, nt;
  if (XCD_SWZ) {
    int lin = blockIdx.y * gridDim.x + blockIdx.x;
    int cpx = (gridDim.x * gridDim.y) >> 3;  // nwg % 8 == 0 required
    int swz = (lin & 7) * cpx + (lin >> 3);
    nt = swz % gridDim.x;
    mt = swz / gridDim.x;
  } else {
    nt = blockIdx.x;
    mt = blockIdx.y;
  }
  const int m0 = mt * 64, n0 = nt * 64;
  const int kBegin = blockIdx.z * kChunk;

  const char* srcA[2];
  const char* srcB[2];
  int dstOff[2];
#pragma unroll
  for (int t = 0; t < 2; ++t) {
    int o = wv * 2048 + t * 1024 + lane * 16;  // linear LDS byte offset
    int row = o >> 7;                          // tile row (128B per row)
    int gcb = (o & 127) ^ ((row & 7) << 4);    // inverse-swizzled global col
    srcA[t] = (const char*)A + ((size_t)(m0 + row) * K + kBegin) * 2 + gcb;
    srcB[t] = (const char*)B + ((size_t)(n0 + row) * K + kBegin) * 2 + gcb;
    dstOff[t] = wv * 2048 + t * 1024;
  }

  const int xorv = (lane & 7) << 4;
  const int rowOff = (lane & 15) * 128;
  const int colHi = (lane >> 4) << 4;

  f32x4 acc[2][2] = {};
  const int nk = kChunk >> 6;
  for (int kt = 0; kt < nk; ++kt) {
#pragma unroll
    for (int t = 0; t < 2; ++t) gload_lds16(srcA[t], lds + dstOff[t]);
#pragma unroll
    for (int t = 0; t < 2; ++t) gload_lds16(srcB[t], lds + 8192 + dstOff[t]);
#pragma unroll
    for (int t = 0; t < 2; ++t) {
      srcA[t] += 128;
      srcB[t] += 128;
    }
    __syncthreads();
#pragma unroll
    for (int h = 0; h < 2; ++h) {
      const int kk64 = h * 64;
      bf16x8 af[2], bfr[2];
#pragma unroll
      for (int f = 0; f < 2; ++f)
        af[f] = *reinterpret_cast<const bf16x8*>(
            lds + ((wm * 32 + f * 16) * 128) + rowOff + ((kk64 + colHi) ^ xorv));
#pragma unroll
      for (int f = 0; f < 2; ++f)
        bfr[f] = *reinterpret_cast<const bf16x8*>(
            lds + 8192 + ((wn * 32 + f * 16) * 128) + rowOff +
            ((kk64 + colHi) ^ xorv));
      __builtin_amdgcn_s_setprio(1);
#pragma unroll
      for (int m = 0; m < 2; ++m)
#pragma unroll
        for (int n = 0; n < 2; ++n)
          acc[m][n] = __builtin_amdgcn_mfma_f32_16x16x32_bf16(af[m], bfr[n],
                                                              acc[m][n], 0, 0, 0);
      __builtin_amdgcn_s_setprio(0);
    }
    __syncthreads();
  }

  const int ldC = CONCAT ? (int)(gridDim.z * N) : N;
  const int cOff = CONCAT ? (int)(blockIdx.z * N) : 0;
  char* Cbase = (char*)Cout;
  if (!CONCAT) Cbase += (size_t)blockIdx.z * M * N * (OUT_BF16 ? 2 : 4);
#pragma unroll
  for (int m = 0; m < 2; ++m) {
    const int grow = m0 + wm * 32 + m * 16 + ((lane >> 4) << 2);
#pragma unroll
    for (int n = 0; n < 2; ++n) {
      const int gcol = n0 + wn * 32 + n * 16 + (lane & 15);
#pragma unroll
      for (int r = 0; r < 4; ++r) {
        float v = acc[m][n][r] * scale;
        if (BIAS_MODE == 2) v += bias[gcol];
        if (OUT_BF16)
          ((bf16*)Cbase)[(size_t)(grow + r) * ldC + cOff + gcol] =
              __float2bfloat16(v);
        else
          ((float*)Cbase)[(size_t)(grow + r) * ldC + cOff + gcol] = v;
      }
    }
  }
}

// ---------------------------------------------------------------------------
// merged node, grid 384:
//  blocks [0,256): 64x64-tile Gext assembly from triangular SpG partials.
//    tile (ti,tj); source = (ti,tj) if floor(ti/2)>=floor(tj/2) else
//    transpose of (tj,ti). Sum 8 partials; emit [bf16(G) | bf16(residual)].
//  blocks [256,384): sv_uw — sv = colsum(x) from part; 16 rows of
//    uw = [Wq;Wk].sv per block.
// ---------------------------------------------------------------------------
__global__ __launch_bounds__(256) void gext_svuw(
    const float* __restrict__ Sp, unsigned short* __restrict__ Gext,
    const float* __restrict__ part, const float* __restrict__ Wq,
    const float* __restrict__ Wk, float* __restrict__ uw) {
  __shared__ float tf[64][65];
  __shared__ float svl[1024];
  const int tid = threadIdx.x;
  const int bx = blockIdx.x;
  if (bx < 256) {
    const int ti = bx >> 4, tj = bx & 15;
    const bool mirror = (ti >> 1) < (tj >> 1);
    const int si = mirror ? tj : ti, sj = mirror ? ti : tj;
    const int r = tid >> 4, c4 = (tid & 15) * 4;
#pragma unroll
    for (int pass = 0; pass < 4; ++pass) {
      const int row = pass * 16 + r;
      float g0 = 0.f, g1 = 0.f, g2 = 0.f, g3 = 0.f;
#pragma unroll
      for (int z = 0; z < 8; ++z) {
        float4 f = *reinterpret_cast<const float4*>(
            Sp + ((size_t)z << 20) + (size_t)(si * 64 + row) * 1024 + sj * 64 + c4);
        g0 += f.x;
        g1 += f.y;
        g2 += f.z;
        g3 += f.w;
      }
      if (!mirror) {
        ushort4 hi, lo;
        unsigned short bb;
        bb = bf16_bits(g0); hi.x = bb; lo.x = bf16_bits(g0 - b2f(bb));
        bb = bf16_bits(g1); hi.y = bb; lo.y = bf16_bits(g1 - b2f(bb));
        bb = bf16_bits(g2); hi.z = bb; lo.z = bf16_bits(g2 - b2f(bb));
        bb = bf16_bits(g3); hi.w = bb; lo.w = bf16_bits(g3 - b2f(bb));
        const size_t base = (size_t)(ti * 64 + row) * 2048 + tj * 64 + c4;
        *reinterpret_cast<ushort4*>(Gext + base) = hi;
        *reinterpret_cast<ushort4*>(Gext + base + 1024) = lo;
      } else {
        tf[row][c4] = g0;
        tf[row][c4 + 1] = g1;
        tf[row][c4 + 2] = g2;
        tf[row][c4 + 3] = g3;
      }
    }
    if (mirror) {
      __syncthreads();
#pragma unroll
      for (int pass = 0; pass < 4; ++pass) {
        const int crow = pass * 16 + r;
        ushort4 hi, lo;
        unsigned short bb;
        float g;
        g = tf[c4][crow];     bb = bf16_bits(g); hi.x = bb; lo.x = bf16_bits(g - b2f(bb));
        g = tf[c4 + 1][crow]; bb = bf16_bits(g); hi.y = bb; lo.y = bf16_bits(g - b2f(bb));
        g = tf[c4 + 2][crow]; bb = bf16_bits(g); hi.z = bb; lo.z = bf16_bits(g - b2f(bb));
        g = tf[c4 + 3][crow]; bb = bf16_bits(g); hi.w = bb; lo.w = bf16_bits(g - b2f(bb));
        const size_t base = (size_t)(ti * 64 + crow) * 2048 + tj * 64 + c4;
        *reinterpret_cast<ushort4*>(Gext + base) = hi;
        *reinterpret_cast<ushort4*>(Gext + base + 1024) = lo;
      }
    }
  } else {
    float4 a = {0.f, 0.f, 0.f, 0.f};
    for (int p = 0; p < 128; ++p) {
      float4 f =
          *reinterpret_cast<const float4*>(part + (size_t)p * 1024 + tid * 4);
      a.x += f.x;
      a.y += f.y;
      a.z += f.z;
      a.w += f.w;
    }
    *reinterpret_cast<float4*>(svl + tid * 4) = a;
    __syncthreads();

    const int lane = tid & 63, wv = tid >> 6;
    const int lane16 = lane & 15, rsub = lane >> 4;
    const int row = (bx - 256) * 16 + wv * 4 + rsub;
    const float* W = (row < 1024) ? (Wq + (size_t)row * 1024)
                                  : (Wk + (size_t)(row - 1024) * 1024);
    float acc = 0.f;
#pragma unroll
    for (int q = 0; q < 16; ++q) {
      const int c = (lane16 + q * 16) * 4;
      float4 wv4 = *reinterpret_cast<const float4*>(W + c);
      float4 s4 = *reinterpret_cast<const float4*>(svl + c);
      acc += wv4.x * s4.x + wv4.y * s4.y + wv4.z * s4.z + wv4.w * s4.w;
    }
#pragma unroll
    for (int off = 1; off < 16; off <<= 1) acc += __shfl_xor(acc, off);
    if (lane16 == 0) uw[row] = acc;
  }
}

// ---------------------------------------------------------------------------
// row-softmax over 2 St split-K partials with rank-1 bias corrections and
// fused r[j] = atten[:,j].bv
// ---------------------------------------------------------------------------
__global__ __launch_bounds__(256) void softmax_corr_r(
    const float* __restrict__ Stp, const float* __restrict__ uw,
    const float* __restrict__ bq, const float* __restrict__ bk,
    const float* __restrict__ bv, bf16* __restrict__ At,
    float* __restrict__ rv) {
  const int j = blockIdx.x;
  const int tid = threadIdx.x;
  const int lane = tid & 63, wv = tid >> 6;
  const float a1 = bk[j];
  const float a2 = uw[1024 + j] + 8192.0f * a1;
  const float norm = 0.03125f;  // 1/sqrt(1024)
  float v[4];
#pragma unroll
  for (int t = 0; t < 4; ++t) {
    const int i = tid + 256 * t;
    float s = Stp[(size_t)j * 1024 + i] + Stp[(1ull << 20) + (size_t)j * 1024 + i];
    v[t] = norm * (s + a1 * uw[i] + a2 * bq[i]);
  }
  float m = fmaxf(fmaxf(v[0], v[1]), fmaxf(v[2], v[3]));
#pragma unroll
  for (int off = 32; off; off >>= 1) m = fmaxf(m, __shfl_xor(m, off));
  __shared__ float red[12];
  if (lane == 0) red[wv] = m;
  __syncthreads();
  m = fmaxf(fmaxf(red[0], red[1]), fmaxf(red[2], red[3]));
  float p[4], s = 0.f, pr = 0.f;
#pragma unroll
  for (int t = 0; t < 4; ++t) {
    p[t] = __expf(v[t] - m);
    s += p[t];
    pr += p[t] * bv[tid + 256 * t];
  }
#pragma unroll
  for (int off = 32; off; off >>= 1) {
    s += __shfl_xor(s, off);
    pr += __shfl_xor(pr, off);
  }
  if (lane == 0) {
    red[4 + wv] = s;
    red[8 + wv] = pr;
  }
  __syncthreads();
  const float inv = 1.f / (red[4] + red[5] + red[6] + red[7]);
#pragma unroll
  for (int t = 0; t < 4; ++t)
    At[(size_t)j * 1024 + tid + 256 * t] = __float2bfloat16(p[t] * inv);
  if (tid == 0) rv[j] = (red[8] + red[9] + red[10] + red[11]) * inv;
}

// ---------------------------------------------------------------------------
extern "C" void kernel_launch(void* const* d_in, const int* in_sizes, int n_in,
                              void* d_out, int out_size, void* d_ws,
                              size_t ws_size, hipStream_t stream) {
  const float* x = (const float*)d_in[0];
  const float* Wq = (const float*)d_in[1];
  const float* bq = (const float*)d_in[2];
  const float* Wk = (const float*)d_in[3];
  const float* bk = (const float*)d_in[4];
  const float* Wv = (const float*)d_in[5];
  const float* bv = (const float*)d_in[6];
  (void)in_sizes;
  (void)n_in;
  (void)out_size;
  (void)ws_size;

  char* ws = (char*)d_ws;
  const size_t MB = 1ull << 20;
  bf16* xb = (bf16*)(ws);                // [8192][1024], 16MB
  bf16* xt = (bf16*)(ws + 16 * MB);      // [1024][8192], 16MB
  float* SpG = (float*)(ws + 32 * MB);   // [8][1024][1024] f32, 32MB (tri)
  bf16* Wkext = (bf16*)(ws + 64 * MB);   // [1024][2048] ([Wk|Wk]), 4MB
  bf16* Wqx2 = (bf16*)(ws + 68 * MB);    // [1024][2048] ([Wq|Wq]), 4MB
  bf16* Wvtb = (bf16*)(ws + 72 * MB);    // [1024][1024] (Wv^T), 2MB
  bf16* Gext = (bf16*)(ws + 74 * MB);    // [1024][2048], 4MB
  bf16* T1x = (bf16*)(ws + 78 * MB);     // [1024][2048] (T1 z-concat), 4MB
  float* Stp = (float*)(ws + 82 * MB);   // [2][1024][1024] f32, 8MB
  bf16* At = (bf16*)(ws + 90 * MB);      // [1024][1024], 2MB
  bf16* Ftb = (bf16*)(ws + 92 * MB);     // [1024][1024], 2MB
  float* uw = (float*)(ws + 94 * MB);           // [2048]
  float* rv = (float*)(ws + 94 * MB + 16384);   // [1024]
  float* part = (float*)(ws + 95 * MB);         // [128][1024] f32, 512KB

  // 1. x -> xb, xt, part; weights -> Wqx2, Wkext, Wvtb (one kernel)
  pre_all<<<dim3(16, 176), 256, 0, stream>>>(
      x, Wq, Wk, Wv, (unsigned short*)xb, (unsigned short*)xt, part,
      (unsigned short*)Wqx2, (unsigned short*)Wkext, (unsigned short*)Wvtb);
  // 2. G = x^T x lower-triangle: TRI grid 288 (36 pairs x 8 K-chunks)
  gemm_nt<0, 0, 0, 0, 1><<<288, 256, 0, stream>>>(
      xt, xt, nullptr, SpG, 1024, 1024, 8192, 1024, 1.0f);
  // 3. Gext = [bf16(G)|residual] (mirrored from triangle) + uw (one node)
  gext_svuw<<<384, 256, 0, stream>>>(SpG, (unsigned short*)Gext, part, Wq, Wk,
                                     uw);
  // 4. T1 = Wk*G: K=2048 split-K=2, bf16 col-concat -> T1x[1024][2048]
  gemm_nt64<0, 1, 1, 1><<<dim3(16, 16, 2), 256, 0, stream>>>(
      Wkext, Gext, nullptr, T1x, 1024, 1024, 2048, 1024, 1.0f);
  // 5. St = T1x * Wqx2^T (K=2048), split-K=2 -> f32 partials (512 blocks)
  gemm_nt64<0, 0, 1, 0><<<dim3(16, 16, 2), 256, 0, stream>>>(
      T1x, Wqx2, nullptr, Stp, 1024, 1024, 2048, 1024, 1.0f);
  // 6. atten^T = softmax(sum partials + corrections); r = atten^T.bv
  softmax_corr_r<<<1024, 256, 0, stream>>>(Stp, uw, bq, bk, bv, At, rv);
  // 7. F^T = NT(At, Wvt) -> bf16   (F = Wv^T atten)  (256 blocks)
  gemm_nt64<0, 1, 1, 0><<<dim3(16, 16), 256, 0, stream>>>(
      At, Wvtb, nullptr, Ftb, 1024, 1024, 1024, 1024, 1.0f);
  // 8. out = x * F + 1*r^T : NT(xb, Ftb) + bias[col] -> f32 d_out
  gemm_nt<2, 0, 1, 0, 0><<<dim3(8, 64), 256, 0, stream>>>(
      xb, Ftb, rv, d_out, 8192, 1024, 1024, 1024, 1.0f);
}